// Round 1
// baseline (680.295 us; speedup 1.0000x reference)
//
#include <hip/hip_runtime.h>

// Problem constants (match reference setup_inputs)
#define NB 128
#define NL 512
#define NN 1023
#define NT 511
#define ND 256
#define NC 511
#define EPSF 1e-6f

// Source encoding:
//   SRC_ZERO          -> zero vector
//   0..511            -> leaf row r (leafbuf)
//   SLOTC + t         -> output slot of type-2 step t (outbuf)
//   STEPC + t         -> unresolved reference to writer step t (resolution only)
#define SRC_ZERO (-1)
#define SLOTC 4096
#define STEPC 8192

// Schedule blob offsets (ints), staged at out + (b*1023+512)*511 ints.
// Overwritten by gemm_internal (launch 3) AFTER exec (launch 2) consumed it.
#define OFF_MAXD 0
#define OFF_OFFS 8
#define OFF_S 524
#define OFF_L 1036
#define OFF_R 1548
#define OFF_F 2060

typedef __attribute__((ext_vector_type(8))) short short8;   // 8 x bf16
typedef __attribute__((ext_vector_type(4))) float f32x4;    // MFMA accumulator
typedef __attribute__((ext_vector_type(2))) float f32x2;    // packed fp32 (v_pk_fma_f32)

__device__ __forceinline__ unsigned short f2bf(float f) {
  unsigned u = __builtin_bit_cast(unsigned, f);
  u += 0x7FFFu + ((u >> 16) & 1u);   // round-to-nearest-even
  return (unsigned short)(u >> 16);
}

// ---------------------------------------------------------------------------
// Resolution shared state (~38.4 KB)
// ---------------------------------------------------------------------------
struct ResolveSh {
  int4 sinfo4[NT];
  int lwl[NT], lwr[NT], fwr[NT];
  int ptr_[NT];
  int lsA[NT], rsA[NT];
  int lvl[NT], fsrc[NT];
  int schedS[NT], schedL[NT], schedR[NT];
  int offs[512], cnt[512], cnt2[512];
  unsigned char deadF[NT], liveF[NT], lzero[512];
  int changed, smax;
};

// ---------------------------------------------------------------------------
// Launch 1: heterogeneous blocks @512 threads.
//   blocks [0,128)        : per-batch dataflow resolution -> schedule in d_out
//   blocks [128,8320)     : embed_scatter, 8 rows/block
//   blocks [8320,8352)    : lin_weight -> bf16 padded
// Resolution depends only on (info, lcid, cmask) -> overlaps embed fully.
// ---------------------------------------------------------------------------
__global__ void __launch_bounds__(512) prep_kernel(
    const int* __restrict__ info, const int* __restrict__ lcid,
    const int* __restrict__ cmask, const float* __restrict__ emb,
    const float* __restrict__ lw, float* __restrict__ leafbuf,
    unsigned short* __restrict__ vecb, unsigned short* __restrict__ wb,
    int* __restrict__ schedO) {
  __shared__ ResolveSh sh;
  const int bid = blockIdx.x;
  const int tid = threadIdx.x;

  if (bid >= 8320) {                 // ---- cvt_w ----
    int i   = (bid - 8320) * 512 + tid;      // [0,16384)
    int row = i >> 5;
    uint4 r = {0u, 0u, 0u, 0u};
    if (row < NC) {
      const float4* v4 = (const float4*)lw;
      float4 x = v4[2 * i], y = v4[2 * i + 1];
      r.x = (unsigned)f2bf(x.x) | ((unsigned)f2bf(x.y) << 16);
      r.y = (unsigned)f2bf(x.z) | ((unsigned)f2bf(x.w) << 16);
      r.z = (unsigned)f2bf(y.x) | ((unsigned)f2bf(y.y) << 16);
      r.w = (unsigned)f2bf(y.z) | ((unsigned)f2bf(y.w) << 16);
    }
    ((uint4*)wb)[i] = r;
    return;
  }

  if (bid >= 128) {                  // ---- embed_scatter (8 waves = 8 rows) ----
    int rid  = (bid - 128) * 8 + (tid >> 6);   // b*NL + l
    int lane = tid & 63;
    int slot = lcid[2 * rid];
    int vid  = lcid[2 * rid + 1];
    int msk  = cmask[rid];
    int b    = rid >> 9;
    float4 v = {0.f, 0.f, 0.f, 0.f};
    if (msk) v = ((const float4*)(emb + (size_t)vid * ND))[lane];
    float ss = v.x * v.x + v.y * v.y + v.z * v.z + v.w * v.w;
#pragma unroll
    for (int off = 32; off > 0; off >>= 1) ss += __shfl_down(ss, off, 64);
    ss = __shfl(ss, 0, 64);
    float inv = 1.0f / (sqrtf(ss) + EPSF);
    float4 o;
    o.x = v.x * inv; o.y = v.y * inv; o.z = v.z * inv; o.w = v.w * inv;
    ((float4*)(leafbuf + ((size_t)b * 512 + slot) * ND))[lane] = o;
    uint2 pk;
    pk.x = (unsigned)f2bf(o.x) | ((unsigned)f2bf(o.y) << 16);
    pk.y = (unsigned)f2bf(o.z) | ((unsigned)f2bf(o.w) << 16);
    ((uint2*)(vecb + ((size_t)b * NN + slot) * ND))[lane] = pk;
    return;
  }

  // ---- resolution for batch b = bid (512 threads, t = tid) ----
  const int b = bid;
  const int4* ib4 = (const int4*)(info + (size_t)b * NT * 4);
  for (int i = tid; i < NT; i += 512) sh.sinfo4[i] = ib4[i];
  if (tid < 512) sh.lzero[tid] = 1;
  if (tid == 0) sh.smax = 0;
  __syncthreads();
  if (tid < NL) {
    int row = lcid[((size_t)b * NL + tid) * 2];
    sh.lzero[row] = (cmask[(size_t)b * NL + tid] == 0) ? 1 : 0;
  }
  __syncthreads();

  // last-writer scan (broadcast reads; one thread per step)
  const int t = tid;
  int4 m1 = {0, 0, 0, 0};
  if (t < NT) m1 = sh.sinfo4[t];
  int l1 = -1, r1 = -1, f1 = -1;
  const int prow = 512 + t;
  for (int tp = 0; tp < NT; ++tp) {
    int4 wi = sh.sinfo4[tp];
    if (wi.x > 0) {
      if (t < NT && tp < t) { if (wi.y == m1.z) l1 = tp; if (wi.y == m1.w) r1 = tp; }
      if (wi.y == prow) f1 = tp;
    }
  }
  if (t < NT) { sh.lwl[t] = l1; sh.lwr[t] = r1; sh.fwr[t] = f1; }
  __syncthreads();

  // type-1 chain collapse via pointer jumping
  if (t < NT) {
    int v;
    if (m1.x == 2) v = SLOTC + t;
    else if (m1.x == 1) {
      if (m1.z < 512) v = m1.z;
      else v = (l1 >= 0) ? (STEPC + l1) : SRC_ZERO;
    } else v = SRC_ZERO;
    sh.ptr_[t] = v;
  }
  __syncthreads();
  for (int it = 0; it < 10; ++it) {
    int v = 0;
    if (t < NT) { v = sh.ptr_[t]; if (v >= STEPC) v = sh.ptr_[v - STEPC]; }
    __syncthreads();
    if (t < NT) sh.ptr_[t] = v;
    __syncthreads();
  }

  // resolve type-2 operands + final row sources
  auto normv = [&](int v) -> int {
    if (v >= 0 && v < 512 && sh.lzero[v]) return SRC_ZERO;
    return v;
  };
  auto collapseW = [&](int wstep) -> int {
    int v = (sh.sinfo4[wstep].x == 2) ? (SLOTC + wstep) : sh.ptr_[wstep];
    return normv(v);
  };
  if (t < NT) {
    if (m1.x == 2) {
      int a = (m1.z < 512) ? normv(m1.z) : ((l1 >= 0) ? collapseW(l1) : SRC_ZERO);
      int c = (m1.w < 512) ? normv(m1.w) : ((r1 >= 0) ? collapseW(r1) : SRC_ZERO);
      sh.lsA[t] = a; sh.rsA[t] = c;
      sh.deadF[t] = (a == SRC_ZERO || c == SRC_ZERO) ? 1 : 0;
    } else {
      sh.deadF[t] = 0;
    }
    sh.liveF[t] = 0;
    sh.fsrc[t] = (f1 >= 0) ? collapseW(f1) : SRC_ZERO;
  }
  __syncthreads();

  // zero propagation fixpoint
  for (int rounds = 0; rounds < NT; ++rounds) {
    if (tid == 0) sh.changed = 0;
    __syncthreads();
    if (t < NT && m1.x == 2 && !sh.deadF[t]) {
      int a = sh.lsA[t], c = sh.rsA[t];
      if (a >= SLOTC && sh.deadF[a - SLOTC]) { a = SRC_ZERO; sh.lsA[t] = a; }
      if (c >= SLOTC && sh.deadF[c - SLOTC]) { c = SRC_ZERO; sh.rsA[t] = c; }
      if (a == SRC_ZERO || c == SRC_ZERO) { sh.deadF[t] = 1; sh.changed = 1; }
    }
    __syncthreads();
    if (!sh.changed) break;
    __syncthreads();
  }

  // backward liveness
  if (t < NT) {
    int f = sh.fsrc[t];
    if (f >= SLOTC && sh.deadF[f - SLOTC]) { f = SRC_ZERO; sh.fsrc[t] = f; }
    if (f >= SLOTC) sh.liveF[f - SLOTC] = 1;
  }
  __syncthreads();
  for (int rounds = 0; rounds < NT; ++rounds) {
    if (tid == 0) sh.changed = 0;
    __syncthreads();
    if (t < NT && m1.x == 2 && sh.liveF[t] && !sh.deadF[t]) {
      int a = sh.lsA[t], c = sh.rsA[t];
      if (a >= SLOTC && !sh.liveF[a - SLOTC]) { sh.liveF[a - SLOTC] = 1; sh.changed = 1; }
      if (c >= SLOTC && !sh.liveF[c - SLOTC]) { sh.liveF[c - SLOTC] = 1; sh.changed = 1; }
    }
    __syncthreads();
    if (!sh.changed) break;
    __syncthreads();
  }

  const bool isLive = (t < NT && m1.x == 2 && sh.liveF[t] && !sh.deadF[t]);

  // ASAP levels via monotone fixpoint
  if (t < NT) sh.lvl[t] = 0;
  __syncthreads();
  for (int rounds = 0; rounds < NT; ++rounds) {
    if (tid == 0) sh.changed = 0;
    __syncthreads();
    if (isLive) {
      int nl = 1, a = sh.lsA[t], c = sh.rsA[t];
      if (a >= SLOTC) { int dl = sh.lvl[a - SLOTC] + 1; if (dl > nl) nl = dl; }
      if (c >= SLOTC) { int dl = sh.lvl[c - SLOTC] + 1; if (dl > nl) nl = dl; }
      if (nl > sh.lvl[t]) { sh.lvl[t] = nl; sh.changed = 1; }
    }
    __syncthreads();
    if (!sh.changed) break;
    __syncthreads();
  }
  if (isLive) atomicMax(&sh.smax, sh.lvl[t]);

  // bucket ops by level
  if (tid < 512) { sh.cnt[tid] = 0; sh.cnt2[tid] = 0; }
  __syncthreads();
  if (isLive) atomicAdd(&sh.cnt[sh.lvl[t]], 1);
  __syncthreads();
  if (tid < 512) sh.offs[tid] = sh.cnt[tid];
  __syncthreads();
  for (int k = 1; k < 512; k <<= 1) {
    int v = 0;
    if (tid < 512) { v = sh.offs[tid]; if (tid >= k) v += sh.offs[tid - k]; }
    __syncthreads();
    if (tid < 512) sh.offs[tid] = v;
    __syncthreads();
  }
  if (isLive) {
    int d = sh.lvl[t];
    int pos = sh.offs[d - 1] + atomicAdd(&sh.cnt2[d], 1);
    sh.schedS[pos] = t; sh.schedL[pos] = sh.lsA[t]; sh.schedR[pos] = sh.rsA[t];
  }
  __syncthreads();

  // export schedule blob to d_out's internal-row region for this batch
  int* g = schedO + ((size_t)b * NN + 512) * NC;
  for (int i = tid; i < NT; i += 512) {
    g[OFF_S + i] = sh.schedS[i];
    g[OFF_L + i] = sh.schedL[i];
    g[OFF_R + i] = sh.schedR[i];
    g[OFF_F + i] = sh.fsrc[i];
  }
  g[OFF_OFFS + tid] = sh.offs[tid];
  if (tid == 0) g[OFF_MAXD] = sh.smax;
}

// ---------------------------------------------------------------------------
// Launch 2 shared state: exec (~58 KB) vs leaf-gemm (48 KB) union.
// ---------------------------------------------------------------------------
struct ExecSh {
  int schedS[NT], schedL[NT], schedR[NT];
  int offs[512];
  int fsrc[NT];
  int maxd;
  float a_st[16][256];
  float b_st[16][512];
};
struct GemmSh {
  short As[256 * 64];
  short Ws[128 * 64];
};
union Sh2 { ExecSh e; GemmSh g; };

// ---------------------------------------------------------------------------
// Launch 2: heterogeneous blocks @1024 threads.
//   blocks [0,128)     : level-parallel compose exec + fused bf16 gather tail
//   blocks [128,1152)  : leaf-half GEMM (out rows n<512), hidden under exec
// ---------------------------------------------------------------------------
__global__ void __launch_bounds__(1024) exec_kernel(
    const float* __restrict__ leafbuf, float* __restrict__ outbuf,
    unsigned short* __restrict__ vecb, const short* __restrict__ wbs,
    const float* __restrict__ bias, float* __restrict__ out,
    const int* __restrict__ schedI) {
  __shared__ Sh2 sh;
  const int tid  = threadIdx.x;
  const int lane = tid & 63;
  const int wav  = tid >> 6;

  if (blockIdx.x < NB) {
    // ---- exec ----
    const int b = blockIdx.x;
    const float* lb = leafbuf + (size_t)b * 512 * ND;
    float*       ob = outbuf + (size_t)b * NT * ND;
    const int*   g  = schedI + ((size_t)b * NN + 512) * NC;
    for (int i = tid; i < NT; i += 1024) {
      sh.e.schedS[i] = g[OFF_S + i];
      sh.e.schedL[i] = g[OFF_L + i];
      sh.e.schedR[i] = g[OFF_R + i];
      sh.e.fsrc[i]   = g[OFF_F + i];
    }
    if (tid < 512) sh.e.offs[tid] = g[OFF_OFFS + tid];
    if (tid == 0) sh.e.maxd = g[OFF_MAXD];
    __syncthreads();
    const int maxd = sh.e.maxd;

    for (int d = 1; d <= maxd; ++d) {
      const int base = sh.e.offs[d - 1];
      const int nops = sh.e.offs[d] - base;
      const int nch  = (nops + 15) >> 4;
      for (int ch = 0; ch < nch; ++ch) {
        int rel = ch * 16 + wav;
        if (rel < nops) {           // wave-uniform predicate
          int my = base + rel;
          int tt = sh.e.schedS[my], ls = sh.e.schedL[my], rs = sh.e.schedR[my];
          const float* pa = (ls < 512) ? lb + (size_t)ls * ND
                                       : ob + (size_t)(ls - SLOTC) * ND;
          const float* pb = (rs < 512) ? lb + (size_t)rs * ND
                                       : ob + (size_t)(rs - SLOTC) * ND;
          float4 av = ((const float4*)pa)[lane];
          float4 bv = ((const float4*)pb)[lane];
          ((float4*)sh.e.a_st[wav])[lane]      = av;
          ((float4*)sh.e.b_st[wav])[lane]      = bv;
          ((float4*)sh.e.b_st[wav])[lane + 64] = bv;   // doubled window
          const float4* a4 = (const float4*)sh.e.a_st[wav];
          const float4* b4 = (const float4*)sh.e.b_st[wav];
          // c[4*lane+r] = sum_j a[j] * b[(j + 4*lane + r) & 255]
          // packed fp32 pairs -> v_pk_fma_f32; per-accumulator order identical
          f32x2 p01 = {0.f, 0.f}, p23 = {0.f, 0.f};
          float4 B0 = b4[lane];
#pragma unroll 8
          for (int i = 0; i < 64; ++i) {
            float4 A  = a4[i];             // uniform -> LDS broadcast
            float4 B1 = b4[lane + i + 1];  // rolling window, conflict-free
            f32x2 ax = {A.x, A.x}, ay = {A.y, A.y}, az = {A.z, A.z}, aw = {A.w, A.w};
            f32x2 b01  = {B0.x, B0.y}, b23  = {B0.z, B0.w};
            f32x2 b12  = {B0.y, B0.z}, b3n0 = {B0.w, B1.x};
            f32x2 bn01 = {B1.x, B1.y}, bn12 = {B1.y, B1.z};
            p01 += ax * b01;  p23 += ax * b23;
            p01 += ay * b12;  p23 += ay * b3n0;
            p01 += az * b23;  p23 += az * bn01;
            p01 += aw * b3n0; p23 += aw * bn12;
            B0 = B1;
          }
          float c0 = p01.x, c1 = p01.y, c2 = p23.x, c3 = p23.y;
          float ss = c0 * c0 + c1 * c1 + c2 * c2 + c3 * c3;
#pragma unroll
          for (int off = 32; off > 0; off >>= 1) ss += __shfl_down(ss, off, 64);
          ss = __shfl(ss, 0, 64);
          float inv = 1.f / (sqrtf(ss) + EPSF);
          float4 res;
          res.x = c0 * inv; res.y = c1 * inv; res.z = c2 * inv; res.w = c3 * inv;
          ((float4*)(ob + (size_t)tt * ND))[lane] = res;
        }
      }
      __syncthreads();   // level boundary
    }

    // ---- fused gather tail: parent rows -> vecb bf16 (fsrc in LDS) ----
    for (int i = wav; i < NT; i += 16) {
      int s = sh.e.fsrc[i];
      float4 v = {0.f, 0.f, 0.f, 0.f};
      if (s >= 0) {
        const float* src = (s < 512) ? lb + (size_t)s * ND
                                     : ob + (size_t)(s - SLOTC) * ND;
        v = ((const float4*)src)[lane];
      }
      uint2 pk;
      pk.x = (unsigned)f2bf(v.x) | ((unsigned)f2bf(v.y) << 16);
      pk.y = (unsigned)f2bf(v.z) | ((unsigned)f2bf(v.w) << 16);
      ((uint2*)(vecb + ((size_t)b * NN + 512 + i) * ND))[lane] = pk;
    }
    return;
  }

  // ---- leaf-half GEMM: 256x128 tile, 16 waves (8x2), rows n<512 only ----
  const int gidx = blockIdx.x - NB;
  const int b  = gidx >> 3;
  const int mt = (gidx >> 2) & 1;     // 2 m-tiles of 256 leaf rows
  const int ct = gidx & 3;            // 4 col-tiles of 128
  const short* A = (const short*)vecb + ((size_t)b * NN + mt * 256) * ND;
  const int c0   = ct * 128;
  const int wr   = wav >> 1;          // 0..7 : 32-row strip
  const int wc   = wav & 1;           // 0..1 : 64-col strip
  const int frow = lane & 15;
  const int quad = lane >> 4;
  f32x4 acc[2][4];
#pragma unroll
  for (int i = 0; i < 2; ++i)
#pragma unroll
    for (int j = 0; j < 4; ++j) acc[i][j] = (f32x4){0.f, 0.f, 0.f, 0.f};

  for (int k0 = 0; k0 < ND; k0 += 64) {
#pragma unroll
    for (int i = 0; i < 2; ++i) {
      int idx = i * 1024 + tid;
      int row = idx >> 3;
      int chn = idx & 7;
      const short* ga = A + (size_t)row * ND + k0 + chn * 8;
      __builtin_amdgcn_global_load_lds(
          (const __attribute__((address_space(1))) void*)ga,
          (__attribute__((address_space(3))) void*)(sh.g.As + idx * 8), 16, 0, 0);
    }
    {
      int row = tid >> 3;
      int chn = tid & 7;
      const short* gw = wbs + (size_t)(c0 + row) * ND + k0 + chn * 8;
      __builtin_amdgcn_global_load_lds(
          (const __attribute__((address_space(1))) void*)gw,
          (__attribute__((address_space(3))) void*)(sh.g.Ws + tid * 8), 16, 0, 0);
    }
    __syncthreads();
#pragma unroll
    for (int ks = 0; ks < 2; ++ks) {
      short8 af[2], wf[4];
#pragma unroll
      for (int mi = 0; mi < 2; ++mi)
        af[mi] = *(const short8*)(sh.g.As + (wr * 32 + mi * 16 + frow) * 64 + ks * 32 + quad * 8);
#pragma unroll
      for (int ci = 0; ci < 4; ++ci)
        wf[ci] = *(const short8*)(sh.g.Ws + (wc * 64 + ci * 16 + frow) * 64 + ks * 32 + quad * 8);
#pragma unroll
      for (int mi = 0; mi < 2; ++mi)
#pragma unroll
        for (int ci = 0; ci < 4; ++ci)
          acc[mi][ci] = __builtin_amdgcn_mfma_f32_16x16x32_bf16(
              af[mi], wf[ci], acc[mi][ci], 0, 0, 0);
    }
    __syncthreads();
  }
#pragma unroll
  for (int mi = 0; mi < 2; ++mi) {
#pragma unroll
    for (int ci = 0; ci < 4; ++ci) {
      int col = c0 + wc * 64 + ci * 16 + frow;
      if (col < NC) {
        float bv = bias[col];
#pragma unroll
        for (int r = 0; r < 4; ++r) {
          int n = mt * 256 + wr * 32 + mi * 16 + quad * 4 + r;   // < 512
          out[((size_t)b * NN + n) * NC + col] = acc[mi][ci][r] + bv;
        }
      }
    }
  }
}

// ---------------------------------------------------------------------------
// Launch 3: internal-row GEMM (n in [512,1023)). 128x128 tile, BK=64.
// Grid (4, 512): by -> (b = by>>2, mt = by&3). Last m-tile has 127 rows; the
// overrun A-row read lands in the wb region of ws (harmless, store-guarded).
// Overwrites the schedule staging bytes in d_out.
// ---------------------------------------------------------------------------
__global__ void __launch_bounds__(256) gemm_internal(
    const short* __restrict__ A, const short* __restrict__ W,
    const float* __restrict__ bias, float* __restrict__ out) {
  __shared__ short As[128 * 64];
  __shared__ short Ws[128 * 64];
  int tid  = threadIdx.x;
  int lane = tid & 63;
  int w    = tid >> 6;
  int c0   = blockIdx.x * 128;
  int b    = blockIdx.y >> 2;
  int mt   = blockIdx.y & 3;
  size_t mbase = (size_t)b * NN + 512 + mt * 128;
  int wm   = (w & 1) * 64;
  int wc   = (w >> 1) * 64;
  int frow = lane & 15;
  int quad = lane >> 4;
  f32x4 acc[4][4];
#pragma unroll
  for (int i = 0; i < 4; ++i)
#pragma unroll
    for (int j = 0; j < 4; ++j) acc[i][j] = (f32x4){0.f, 0.f, 0.f, 0.f};

  for (int k0 = 0; k0 < ND; k0 += 64) {
#pragma unroll
    for (int i = 0; i < 4; ++i) {
      int idx = i * 256 + tid;
      int row = idx >> 3;
      int chn = idx & 7;
      const short* ga = A + (mbase + row) * ND + k0 + chn * 8;
      const short* gw = W + (size_t)(c0 + row) * ND + k0 + chn * 8;
      __builtin_amdgcn_global_load_lds(
          (const __attribute__((address_space(1))) void*)ga,
          (__attribute__((address_space(3))) void*)(As + idx * 8), 16, 0, 0);
      __builtin_amdgcn_global_load_lds(
          (const __attribute__((address_space(1))) void*)gw,
          (__attribute__((address_space(3))) void*)(Ws + idx * 8), 16, 0, 0);
    }
    __syncthreads();
#pragma unroll
    for (int ks = 0; ks < 2; ++ks) {
      short8 af[4], wf[4];
#pragma unroll
      for (int mi = 0; mi < 4; ++mi)
        af[mi] = *(const short8*)(As + (wm + mi * 16 + frow) * 64 + ks * 32 + quad * 8);
#pragma unroll
      for (int ci = 0; ci < 4; ++ci)
        wf[ci] = *(const short8*)(Ws + (wc + ci * 16 + frow) * 64 + ks * 32 + quad * 8);
#pragma unroll
      for (int mi = 0; mi < 4; ++mi)
#pragma unroll
        for (int ci = 0; ci < 4; ++ci)
          acc[mi][ci] = __builtin_amdgcn_mfma_f32_16x16x32_bf16(
              af[mi], wf[ci], acc[mi][ci], 0, 0, 0);
    }
    __syncthreads();
  }
#pragma unroll
  for (int mi = 0; mi < 4; ++mi) {
#pragma unroll
    for (int ci = 0; ci < 4; ++ci) {
      int col = c0 + wc + ci * 16 + frow;
      if (col < NC) {
        float bv = bias[col];
#pragma unroll
        for (int r = 0; r < 4; ++r) {
          int n = 512 + mt * 128 + wm + mi * 16 + quad * 4 + r;
          if (n < NN)
            out[((size_t)b * NN + n) * NC + col] = acc[mi][ci][r] + bv;
        }
      }
    }
  }
}

// ---------------------------------------------------------------------------
// Workspace layout (201,392,128 bytes — unchanged):
//   [0)           leafbuf fp32 [B][512][D]  =  67,108,864 B
//   [67108864)    outbuf  fp32 [B][511][D]  =  66,977,792 B
//   [134086656)   vecb    bf16 [B][1023][D] =  67,043,328 B
//   [201129984)   wb      bf16 [512][D]     =     262,144 B
// Schedule blobs staged per-batch in d_out's internal-row region (rows
// n>=512), read by exec (launch 2), overwritten by gemm_internal (launch 3).
// ---------------------------------------------------------------------------
extern "C" void kernel_launch(void* const* d_in, const int* in_sizes, int n_in,
                              void* d_out, int out_size, void* d_ws, size_t ws_size,
                              hipStream_t stream) {
  const int*   lcid  = (const int*)d_in[1];
  const int*   cmask = (const int*)d_in[2];
  const int*   cinfo = (const int*)d_in[3];
  const float* emb   = (const float*)d_in[4];
  const float* lw    = (const float*)d_in[5];
  const float* lbias = (const float*)d_in[6];
  float*       out   = (float*)d_out;

  char* ws = (char*)d_ws;
  float*          leafbuf = (float*)ws;
  float*          outbuf  = (float*)(ws + 67108864);
  unsigned short* vecb    = (unsigned short*)(ws + 134086656);
  unsigned short* wb      = (unsigned short*)(ws + 201129984);

  // L1: resolve (128) + embed (8192) + cvt_w (32) — resolve blocks first
  prep_kernel<<<8352, 512, 0, stream>>>(cinfo, lcid, cmask, emb, lw,
                                        leafbuf, vecb, wb, (int*)d_out);
  // L2: exec (128) + leaf-half gemm (1024)
  exec_kernel<<<1152, 1024, 0, stream>>>(leafbuf, outbuf, vecb,
                                         (const short*)wb, lbias, out,
                                         (const int*)d_out);
  // L3: internal-row gemm
  gemm_internal<<<dim3(4, 512), 256, 0, stream>>>(
      (const short*)vecb, (const short*)wb, lbias, out);
}

// Round 2
// 674.644 us; speedup vs baseline: 1.0084x; 1.0084x over previous
//
#include <hip/hip_runtime.h>

// Problem constants (match reference setup_inputs)
#define NB 128
#define NL 512
#define NN 1023
#define NT 511
#define ND 256
#define NC 511
#define EPSF 1e-6f

// Source encoding:
//   SRC_ZERO          -> zero vector
//   0..511            -> leaf row r (leafbuf)
//   SLOTC + t         -> output slot of type-2 step t (outbuf)
//   STEPC + t         -> unresolved reference to writer step t (resolution only)
#define SRC_ZERO (-1)
#define SLOTC 4096
#define STEPC 8192

// Schedule blob offsets (ints), staged at out + (b*1023+512)*511 ints.
// Read by exec (launch 2), overwritten by gemm (launch 3).
#define OFF_MAXD 0
#define OFF_OFFS 8
#define OFF_S 524
#define OFF_L 1036
#define OFF_R 1548
#define OFF_F 2060

typedef __attribute__((ext_vector_type(8))) short short8;   // 8 x bf16
typedef __attribute__((ext_vector_type(4))) float f32x4;    // MFMA accumulator

__device__ __forceinline__ unsigned short f2bf(float f) {
  unsigned u = __builtin_bit_cast(unsigned, f);
  u += 0x7FFFu + ((u >> 16) & 1u);   // round-to-nearest-even
  return (unsigned short)(u >> 16);
}

// ---------------------------------------------------------------------------
// Resolution shared state (~38.4 KB)
// ---------------------------------------------------------------------------
struct ResolveSh {
  int4 sinfo4[NT];
  int lwl[NT], lwr[NT], fwr[NT];
  int ptr_[NT];
  int lsA[NT], rsA[NT];
  int lvl[NT], fsrc[NT];
  int schedS[NT], schedL[NT], schedR[NT];
  int offs[512], cnt[512], cnt2[512];
  unsigned char deadF[NT], liveF[NT], lzero[512];
  int changed, smax;
};

// ---------------------------------------------------------------------------
// Launch 1: heterogeneous blocks @512 threads.
//   blocks [0,128)        : per-batch dataflow resolution -> schedule in d_out
//   blocks [128,8320)     : embed_scatter, 8 rows/block
//   blocks [8320,8352)    : lin_weight -> bf16 padded
// Resolution depends only on (info, lcid, cmask) -> overlaps embed fully.
// ---------------------------------------------------------------------------
__global__ void __launch_bounds__(512) prep_kernel(
    const int* __restrict__ info, const int* __restrict__ lcid,
    const int* __restrict__ cmask, const float* __restrict__ emb,
    const float* __restrict__ lw, float* __restrict__ leafbuf,
    unsigned short* __restrict__ vecb, unsigned short* __restrict__ wb,
    int* __restrict__ schedO) {
  __shared__ ResolveSh sh;
  const int bid = blockIdx.x;
  const int tid = threadIdx.x;

  if (bid >= 8320) {                 // ---- cvt_w ----
    int i   = (bid - 8320) * 512 + tid;      // [0,16384)
    int row = i >> 5;
    uint4 r = {0u, 0u, 0u, 0u};
    if (row < NC) {
      const float4* v4 = (const float4*)lw;
      float4 x = v4[2 * i], y = v4[2 * i + 1];
      r.x = (unsigned)f2bf(x.x) | ((unsigned)f2bf(x.y) << 16);
      r.y = (unsigned)f2bf(x.z) | ((unsigned)f2bf(x.w) << 16);
      r.z = (unsigned)f2bf(y.x) | ((unsigned)f2bf(y.y) << 16);
      r.w = (unsigned)f2bf(y.z) | ((unsigned)f2bf(y.w) << 16);
    }
    ((uint4*)wb)[i] = r;
    return;
  }

  if (bid >= 128) {                  // ---- embed_scatter (8 waves = 8 rows) ----
    int rid  = (bid - 128) * 8 + (tid >> 6);   // b*NL + l
    int lane = tid & 63;
    int slot = lcid[2 * rid];
    int vid  = lcid[2 * rid + 1];
    int msk  = cmask[rid];
    int b    = rid >> 9;
    float4 v = {0.f, 0.f, 0.f, 0.f};
    if (msk) v = ((const float4*)(emb + (size_t)vid * ND))[lane];
    float ss = v.x * v.x + v.y * v.y + v.z * v.z + v.w * v.w;
#pragma unroll
    for (int off = 32; off > 0; off >>= 1) ss += __shfl_down(ss, off, 64);
    ss = __shfl(ss, 0, 64);
    float inv = 1.0f / (sqrtf(ss) + EPSF);
    float4 o;
    o.x = v.x * inv; o.y = v.y * inv; o.z = v.z * inv; o.w = v.w * inv;
    ((float4*)(leafbuf + ((size_t)b * 512 + slot) * ND))[lane] = o;
    uint2 pk;
    pk.x = (unsigned)f2bf(o.x) | ((unsigned)f2bf(o.y) << 16);
    pk.y = (unsigned)f2bf(o.z) | ((unsigned)f2bf(o.w) << 16);
    ((uint2*)(vecb + ((size_t)b * NN + slot) * ND))[lane] = pk;
    return;
  }

  // ---- resolution for batch b = bid (512 threads, t = tid) ----
  const int b = bid;
  const int4* ib4 = (const int4*)(info + (size_t)b * NT * 4);
  for (int i = tid; i < NT; i += 512) sh.sinfo4[i] = ib4[i];
  if (tid < 512) sh.lzero[tid] = 1;
  if (tid == 0) sh.smax = 0;
  __syncthreads();
  if (tid < NL) {
    int row = lcid[((size_t)b * NL + tid) * 2];
    sh.lzero[row] = (cmask[(size_t)b * NL + tid] == 0) ? 1 : 0;
  }
  __syncthreads();

  // last-writer scan (broadcast reads; one thread per step)
  const int t = tid;
  int4 m1 = {0, 0, 0, 0};
  if (t < NT) m1 = sh.sinfo4[t];
  int l1 = -1, r1 = -1, f1 = -1;
  const int prow = 512 + t;
  for (int tp = 0; tp < NT; ++tp) {
    int4 wi = sh.sinfo4[tp];
    if (wi.x > 0) {
      if (t < NT && tp < t) { if (wi.y == m1.z) l1 = tp; if (wi.y == m1.w) r1 = tp; }
      if (wi.y == prow) f1 = tp;
    }
  }
  if (t < NT) { sh.lwl[t] = l1; sh.lwr[t] = r1; sh.fwr[t] = f1; }
  __syncthreads();

  // type-1 chain collapse via pointer jumping
  if (t < NT) {
    int v;
    if (m1.x == 2) v = SLOTC + t;
    else if (m1.x == 1) {
      if (m1.z < 512) v = m1.z;
      else v = (l1 >= 0) ? (STEPC + l1) : SRC_ZERO;
    } else v = SRC_ZERO;
    sh.ptr_[t] = v;
  }
  __syncthreads();
  for (int it = 0; it < 10; ++it) {
    int v = 0;
    if (t < NT) { v = sh.ptr_[t]; if (v >= STEPC) v = sh.ptr_[v - STEPC]; }
    __syncthreads();
    if (t < NT) sh.ptr_[t] = v;
    __syncthreads();
  }

  // resolve type-2 operands + final row sources
  auto normv = [&](int v) -> int {
    if (v >= 0 && v < 512 && sh.lzero[v]) return SRC_ZERO;
    return v;
  };
  auto collapseW = [&](int wstep) -> int {
    int v = (sh.sinfo4[wstep].x == 2) ? (SLOTC + wstep) : sh.ptr_[wstep];
    return normv(v);
  };
  if (t < NT) {
    if (m1.x == 2) {
      int a = (m1.z < 512) ? normv(m1.z) : ((l1 >= 0) ? collapseW(l1) : SRC_ZERO);
      int c = (m1.w < 512) ? normv(m1.w) : ((r1 >= 0) ? collapseW(r1) : SRC_ZERO);
      sh.lsA[t] = a; sh.rsA[t] = c;
      sh.deadF[t] = (a == SRC_ZERO || c == SRC_ZERO) ? 1 : 0;
    } else {
      sh.deadF[t] = 0;
    }
    sh.liveF[t] = 0;
    sh.fsrc[t] = (f1 >= 0) ? collapseW(f1) : SRC_ZERO;
  }
  __syncthreads();

  // zero propagation fixpoint
  for (int rounds = 0; rounds < NT; ++rounds) {
    if (tid == 0) sh.changed = 0;
    __syncthreads();
    if (t < NT && m1.x == 2 && !sh.deadF[t]) {
      int a = sh.lsA[t], c = sh.rsA[t];
      if (a >= SLOTC && sh.deadF[a - SLOTC]) { a = SRC_ZERO; sh.lsA[t] = a; }
      if (c >= SLOTC && sh.deadF[c - SLOTC]) { c = SRC_ZERO; sh.rsA[t] = c; }
      if (a == SRC_ZERO || c == SRC_ZERO) { sh.deadF[t] = 1; sh.changed = 1; }
    }
    __syncthreads();
    if (!sh.changed) break;
    __syncthreads();
  }

  // backward liveness
  if (t < NT) {
    int f = sh.fsrc[t];
    if (f >= SLOTC && sh.deadF[f - SLOTC]) { f = SRC_ZERO; sh.fsrc[t] = f; }
    if (f >= SLOTC) sh.liveF[f - SLOTC] = 1;
  }
  __syncthreads();
  for (int rounds = 0; rounds < NT; ++rounds) {
    if (tid == 0) sh.changed = 0;
    __syncthreads();
    if (t < NT && m1.x == 2 && sh.liveF[t] && !sh.deadF[t]) {
      int a = sh.lsA[t], c = sh.rsA[t];
      if (a >= SLOTC && !sh.liveF[a - SLOTC]) { sh.liveF[a - SLOTC] = 1; sh.changed = 1; }
      if (c >= SLOTC && !sh.liveF[c - SLOTC]) { sh.liveF[c - SLOTC] = 1; sh.changed = 1; }
    }
    __syncthreads();
    if (!sh.changed) break;
    __syncthreads();
  }

  const bool isLive = (t < NT && m1.x == 2 && sh.liveF[t] && !sh.deadF[t]);

  // ASAP levels via monotone fixpoint
  if (t < NT) sh.lvl[t] = 0;
  __syncthreads();
  for (int rounds = 0; rounds < NT; ++rounds) {
    if (tid == 0) sh.changed = 0;
    __syncthreads();
    if (isLive) {
      int nl = 1, a = sh.lsA[t], c = sh.rsA[t];
      if (a >= SLOTC) { int dl = sh.lvl[a - SLOTC] + 1; if (dl > nl) nl = dl; }
      if (c >= SLOTC) { int dl = sh.lvl[c - SLOTC] + 1; if (dl > nl) nl = dl; }
      if (nl > sh.lvl[t]) { sh.lvl[t] = nl; sh.changed = 1; }
    }
    __syncthreads();
    if (!sh.changed) break;
    __syncthreads();
  }
  if (isLive) atomicMax(&sh.smax, sh.lvl[t]);

  // bucket ops by level
  if (tid < 512) { sh.cnt[tid] = 0; sh.cnt2[tid] = 0; }
  __syncthreads();
  if (isLive) atomicAdd(&sh.cnt[sh.lvl[t]], 1);
  __syncthreads();
  if (tid < 512) sh.offs[tid] = sh.cnt[tid];
  __syncthreads();
  for (int k = 1; k < 512; k <<= 1) {
    int v = 0;
    if (tid < 512) { v = sh.offs[tid]; if (tid >= k) v += sh.offs[tid - k]; }
    __syncthreads();
    if (tid < 512) sh.offs[tid] = v;
    __syncthreads();
  }
  if (isLive) {
    int d = sh.lvl[t];
    int pos = sh.offs[d - 1] + atomicAdd(&sh.cnt2[d], 1);
    sh.schedS[pos] = t; sh.schedL[pos] = sh.lsA[t]; sh.schedR[pos] = sh.rsA[t];
  }
  __syncthreads();

  // export schedule blob to d_out's internal-row region for this batch
  int* g = schedO + ((size_t)b * NN + 512) * NC;
  for (int i = tid; i < NT; i += 512) {
    g[OFF_S + i] = sh.schedS[i];
    g[OFF_L + i] = sh.schedL[i];
    g[OFF_R + i] = sh.schedR[i];
    g[OFF_F + i] = sh.fsrc[i];
  }
  g[OFF_OFFS + tid] = sh.offs[tid];
  if (tid == 0) g[OFF_MAXD] = sh.smax;
}

// ---------------------------------------------------------------------------
// Launch 2 shared state (~58 KB)
// ---------------------------------------------------------------------------
struct ExecSh {
  int schedS[NT], schedL[NT], schedR[NT];
  int offs[512];
  int fsrc[NT];
  int maxd;
  float a_st[16][256];
  float b_st[16][512];
};

// ---------------------------------------------------------------------------
// Launch 2: level-parallel compose exec (one block per batch, 16 waves) with
// the bf16 gather fused as a tail. Standalone: no co-resident GEMM blocks
// competing for the LDS pipe (round-1 lesson). Scalar FMA inner loop (proven).
// ---------------------------------------------------------------------------
__global__ void __launch_bounds__(1024) exec_kernel(
    const float* __restrict__ leafbuf, float* __restrict__ outbuf,
    unsigned short* __restrict__ vecb, const int* __restrict__ schedI) {
  __shared__ ExecSh sh;
  const int tid  = threadIdx.x;
  const int lane = tid & 63;
  const int wav  = tid >> 6;
  const int b    = blockIdx.x;

  const float* lb = leafbuf + (size_t)b * 512 * ND;
  float*       ob = outbuf + (size_t)b * NT * ND;
  const int*   g  = schedI + ((size_t)b * NN + 512) * NC;
  for (int i = tid; i < NT; i += 1024) {
    sh.schedS[i] = g[OFF_S + i];
    sh.schedL[i] = g[OFF_L + i];
    sh.schedR[i] = g[OFF_R + i];
    sh.fsrc[i]   = g[OFF_F + i];
  }
  if (tid < 512) sh.offs[tid] = g[OFF_OFFS + tid];
  if (tid == 0) sh.maxd = g[OFF_MAXD];
  __syncthreads();
  const int maxd = sh.maxd;

  for (int d = 1; d <= maxd; ++d) {
    const int base = sh.offs[d - 1];
    const int nops = sh.offs[d] - base;
    const int nch  = (nops + 15) >> 4;
    for (int ch = 0; ch < nch; ++ch) {
      int rel = ch * 16 + wav;
      if (rel < nops) {           // wave-uniform predicate (depends on wav only)
        int my = base + rel;
        int tt = sh.schedS[my], ls = sh.schedL[my], rs = sh.schedR[my];
        const float* pa = (ls < 512) ? lb + (size_t)ls * ND
                                     : ob + (size_t)(ls - SLOTC) * ND;
        const float* pb = (rs < 512) ? lb + (size_t)rs * ND
                                     : ob + (size_t)(rs - SLOTC) * ND;
        float4 av = ((const float4*)pa)[lane];
        float4 bv = ((const float4*)pb)[lane];
        ((float4*)sh.a_st[wav])[lane]      = av;
        ((float4*)sh.b_st[wav])[lane]      = bv;
        ((float4*)sh.b_st[wav])[lane + 64] = bv;   // doubled for mod-256 window
        const float4* a4 = (const float4*)sh.a_st[wav];
        const float4* b4 = (const float4*)sh.b_st[wav];
        // c[4*lane+r] = sum_j a[j] * b[(j + 4*lane + r) & 255]
        float c0 = 0.f, c1 = 0.f, c2 = 0.f, c3 = 0.f;
        float4 B0 = b4[lane];
#pragma unroll 8
        for (int i = 0; i < 64; ++i) {
          float4 A  = a4[i];             // uniform -> LDS broadcast
          float4 B1 = b4[lane + i + 1];  // rolling window (stride-16B, conflict-free)
          c0 += A.x * B0.x + A.y * B0.y + A.z * B0.z + A.w * B0.w;
          c1 += A.x * B0.y + A.y * B0.z + A.z * B0.w + A.w * B1.x;
          c2 += A.x * B0.z + A.y * B0.w + A.z * B1.x + A.w * B1.y;
          c3 += A.x * B0.w + A.y * B1.x + A.z * B1.y + A.w * B1.z;
          B0 = B1;
        }
        float ss = c0 * c0 + c1 * c1 + c2 * c2 + c3 * c3;
#pragma unroll
        for (int off = 32; off > 0; off >>= 1) ss += __shfl_down(ss, off, 64);
        ss = __shfl(ss, 0, 64);
        float inv = 1.f / (sqrtf(ss) + EPSF);
        float4 res;
        res.x = c0 * inv; res.y = c1 * inv; res.z = c2 * inv; res.w = c3 * inv;
        ((float4*)(ob + (size_t)tt * ND))[lane] = res;
      }
      // no intra-level barrier: staging is wave-private, deps are cross-level
    }
    __syncthreads();   // level boundary: drains stores; next level reads hit L2
  }

  // ---- fused gather tail: parent rows -> vecb bf16 (fsrc in LDS) ----
  for (int i = wav; i < NT; i += 16) {
    int s = sh.fsrc[i];
    float4 v = {0.f, 0.f, 0.f, 0.f};
    if (s >= 0) {
      const float* src = (s < 512) ? lb + (size_t)s * ND
                                   : ob + (size_t)(s - SLOTC) * ND;
      v = ((const float4*)src)[lane];
    }
    uint2 pk;
    pk.x = (unsigned)f2bf(v.x) | ((unsigned)f2bf(v.y) << 16);
    pk.y = (unsigned)f2bf(v.z) | ((unsigned)f2bf(v.w) << 16);
    ((uint2*)(vecb + ((size_t)b * NN + 512 + i) * ND))[lane] = pk;
  }
}

// ---------------------------------------------------------------------------
// Launch 3: full GEMM. out[m][c] = sum_k A[m][k]*W[c][k] + bias[c]
// (A: 130944x256 bf16, W: 512x256 bf16 zero-padded). 128x128 tile, BK=64,
// global_load_lds w=16, mfma_f32_16x16x32_bf16. Grid (4, 1023).
//
// Bank-conflict fix (rule #21 both-sides): LDS dest stays linear; the GLOBAL
// source chunk is pre-swizzled (ch ^= row&7) and the fragment read XORs the
// same involution (chunk = (ks*4+quad) ^ (row&7)). Each 8-lane phase of
// ds_read_b128 then touches 8 distinct 16B slots = all 32 banks (was 16-way).
// ---------------------------------------------------------------------------
__global__ void __launch_bounds__(256) gemm_kernel(
    const short* __restrict__ A, const short* __restrict__ W,
    const float* __restrict__ bias, float* __restrict__ out) {
  __shared__ short As[128 * 64];
  __shared__ short Ws[128 * 64];
  int tid  = threadIdx.x;
  int lane = tid & 63;
  int w    = tid >> 6;
  int c0   = blockIdx.x * 128;
  int m0   = blockIdx.y * 128;
  int wm   = (w & 1) * 64;
  int wc   = (w >> 1) * 64;
  int frow = lane & 15;
  int quad = lane >> 4;
  f32x4 acc[4][4];
#pragma unroll
  for (int i = 0; i < 4; ++i)
#pragma unroll
    for (int j = 0; j < 4; ++j) acc[i][j] = (f32x4){0.f, 0.f, 0.f, 0.f};

  for (int k0 = 0; k0 < ND; k0 += 64) {
#pragma unroll
    for (int i = 0; i < 4; ++i) {
      int idx = i * 256 + tid;
      int row = idx >> 3;
      int ch  = idx & 7;
      int chs = ch ^ (row & 7);   // pre-swizzled source chunk
      const short* ga = A + (size_t)(m0 + row) * ND + k0 + chs * 8;
      const short* gw = W + (size_t)(c0 + row) * ND + k0 + chs * 8;
      __builtin_amdgcn_global_load_lds(
          (const __attribute__((address_space(1))) void*)ga,
          (__attribute__((address_space(3))) void*)(As + idx * 8), 16, 0, 0);
      __builtin_amdgcn_global_load_lds(
          (const __attribute__((address_space(1))) void*)gw,
          (__attribute__((address_space(3))) void*)(Ws + idx * 8), 16, 0, 0);
    }
    __syncthreads();
#pragma unroll
    for (int ks = 0; ks < 2; ++ks) {
      short8 af[4], wf[4];
#pragma unroll
      for (int mi = 0; mi < 4; ++mi) {
        int r = wm + mi * 16 + frow;
        int cc = (ks * 4 + quad) ^ (r & 7);
        af[mi] = *(const short8*)(As + r * 64 + cc * 8);
      }
#pragma unroll
      for (int ci = 0; ci < 4; ++ci) {
        int r = wc + ci * 16 + frow;
        int cc = (ks * 4 + quad) ^ (r & 7);
        wf[ci] = *(const short8*)(Ws + r * 64 + cc * 8);
      }
#pragma unroll
      for (int mi = 0; mi < 4; ++mi)
#pragma unroll
        for (int ci = 0; ci < 4; ++ci)
          acc[mi][ci] = __builtin_amdgcn_mfma_f32_16x16x32_bf16(
              af[mi], wf[ci], acc[mi][ci], 0, 0, 0);
    }
    __syncthreads();
  }
#pragma unroll
  for (int mi = 0; mi < 4; ++mi) {
#pragma unroll
    for (int ci = 0; ci < 4; ++ci) {
      int col = c0 + wc + ci * 16 + frow;
      if (col < NC) {
        float bv = bias[col];
#pragma unroll
        for (int r = 0; r < 4; ++r) {
          int m = m0 + wm + mi * 16 + quad * 4 + r;
          out[(size_t)m * NC + col] = acc[mi][ci][r] + bv;
        }
      }
    }
  }
}

// ---------------------------------------------------------------------------
// Workspace layout (201,392,128 bytes — unchanged):
//   [0)           leafbuf fp32 [B][512][D]  =  67,108,864 B
//   [67108864)    outbuf  fp32 [B][511][D]  =  66,977,792 B
//   [134086656)   vecb    bf16 [B][1023][D] =  67,043,328 B
//   [201129984)   wb      bf16 [512][D]     =     262,144 B
// Schedule blobs staged per-batch in d_out's internal-row region (rows
// n>=512), read by exec (launch 2), overwritten by gemm (launch 3).
// ---------------------------------------------------------------------------
extern "C" void kernel_launch(void* const* d_in, const int* in_sizes, int n_in,
                              void* d_out, int out_size, void* d_ws, size_t ws_size,
                              hipStream_t stream) {
  const int*   lcid  = (const int*)d_in[1];
  const int*   cmask = (const int*)d_in[2];
  const int*   cinfo = (const int*)d_in[3];
  const float* emb   = (const float*)d_in[4];
  const float* lw    = (const float*)d_in[5];
  const float* lbias = (const float*)d_in[6];
  float*       out   = (float*)d_out;

  char* ws = (char*)d_ws;
  float*          leafbuf = (float*)ws;
  float*          outbuf  = (float*)(ws + 67108864);
  unsigned short* vecb    = (unsigned short*)(ws + 134086656);
  unsigned short* wb      = (unsigned short*)(ws + 201129984);

  // L1: resolve (128) + embed (8192) + cvt_w (32) — resolve blocks first
  prep_kernel<<<8352, 512, 0, stream>>>(cinfo, lcid, cmask, emb, lw,
                                        leafbuf, vecb, wb, (int*)d_out);
  // L2: compose exec + fused gather (standalone: no CU co-tenancy)
  exec_kernel<<<NB, 1024, 0, stream>>>(leafbuf, outbuf, vecb,
                                       (const int*)d_out);
  // L3: full GEMM, bank-conflict-free fragment reads
  gemm_kernel<<<dim3(4, 1023), 256, 0, stream>>>(
      (const short*)vecb, (const short*)wb, lbias, out);
}

// Round 5
// 559.510 us; speedup vs baseline: 1.2159x; 1.2058x over previous
//
#include <hip/hip_runtime.h>

// Problem constants (match reference setup_inputs)
#define NB 128
#define NL 512
#define NN 1023
#define NT 511
#define ND 256
#define NC 511
#define EPSF 1e-6f

// Source encoding:
//   SRC_ZERO          -> zero vector
//   0..511            -> leaf row r (leafbuf)
//   SLOTC + t         -> output slot of type-2 step t (outbuf)
//   STEPC + t         -> unresolved reference to writer step t (resolution only)
#define SRC_ZERO (-1)
#define SLOTC 4096
#define STEPC 8192

typedef __attribute__((ext_vector_type(8))) short short8;   // 8 x bf16
typedef __attribute__((ext_vector_type(4))) float f32x4;    // MFMA accumulator

__device__ __forceinline__ unsigned short f2bf(float f) {
  unsigned u = __builtin_bit_cast(unsigned, f);
  u += 0x7FFFu + ((u >> 16) & 1u);   // round-to-nearest-even
  return (unsigned short)(u >> 16);
}

// ---------------------------------------------------------------------------
// Phase 1: embed (normalize emb rows -> leafbuf fp32 + vecb bf16) and cvt_w,
// merged into one launch. blocks [0,16384): embed (4 rows/block);
// blocks [16384,16448): lin_weight -> bf16 padded to 512 rows.
// (Both halves are instruction-identical to the round-0 proven kernels.)
// ---------------------------------------------------------------------------
__global__ void __launch_bounds__(256) embed_scatter(
    const int* __restrict__ lcid, const int* __restrict__ cmask,
    const float* __restrict__ emb, const float* __restrict__ lw,
    float* __restrict__ leafbuf, unsigned short* __restrict__ vecb,
    unsigned short* __restrict__ wb) {
  if (blockIdx.x >= 16384) {          // ---- cvt_w ----
    int i   = (blockIdx.x - 16384) * 256 + threadIdx.x;   // [0,16384)
    int row = i >> 5;
    uint4 r = {0u, 0u, 0u, 0u};
    if (row < NC) {
      const float4* v4 = (const float4*)lw;
      float4 x = v4[2 * i], y = v4[2 * i + 1];
      r.x = (unsigned)f2bf(x.x) | ((unsigned)f2bf(x.y) << 16);
      r.y = (unsigned)f2bf(x.z) | ((unsigned)f2bf(x.w) << 16);
      r.z = (unsigned)f2bf(y.x) | ((unsigned)f2bf(y.y) << 16);
      r.w = (unsigned)f2bf(y.z) | ((unsigned)f2bf(y.w) << 16);
    }
    ((uint4*)wb)[i] = r;
    return;
  }
  int rid  = blockIdx.x * 4 + (threadIdx.x >> 6);   // b*NL + l
  int lane = threadIdx.x & 63;
  int slot = lcid[2 * rid];
  int vid  = lcid[2 * rid + 1];
  int msk  = cmask[rid];
  int b    = rid >> 9;                               // / NL
  float4 v = {0.f, 0.f, 0.f, 0.f};
  if (msk) v = ((const float4*)(emb + (size_t)vid * ND))[lane];
  float ss = v.x * v.x + v.y * v.y + v.z * v.z + v.w * v.w;
#pragma unroll
  for (int off = 32; off > 0; off >>= 1) ss += __shfl_down(ss, off, 64);
  ss = __shfl(ss, 0, 64);
  float inv = 1.0f / (sqrtf(ss) + EPSF);   // msk==0: v=0 -> o=0 (no NaN)
  float4 o;
  o.x = v.x * inv; o.y = v.y * inv; o.z = v.z * inv; o.w = v.w * inv;
  ((float4*)(leafbuf + ((size_t)b * 512 + slot) * ND))[lane] = o;
  uint2 pk;
  pk.x = (unsigned)f2bf(o.x) | ((unsigned)f2bf(o.y) << 16);
  pk.y = (unsigned)f2bf(o.z) | ((unsigned)f2bf(o.w) << 16);
  ((uint2*)(vecb + ((size_t)b * NN + slot) * ND))[lane] = pk;
}

// ---------------------------------------------------------------------------
// Phase 2: compose — EXACT round-0 proven kernel (one op per wave).
// One block (1024 threads = 16 waves) per batch.
// ---------------------------------------------------------------------------
__global__ void __launch_bounds__(1024) compose_kernel(
    const int* __restrict__ info, const int* __restrict__ lcid,
    const int* __restrict__ cmask, const float* __restrict__ leafbuf,
    float* __restrict__ outbuf, int* __restrict__ fsrcG) {
  const int b    = blockIdx.x;
  const int tid  = threadIdx.x;
  const int lane = tid & 63;
  const int wav  = tid >> 6;

  __shared__ int4 sinfo4[NT];                 // (ctype, parent, lchild, rchild)
  __shared__ int lwl[NT], lwr[NT], fwr[NT];   // last writers
  __shared__ int ptr_[NT];                    // type-1 chain terminal
  __shared__ int lsA[NT], rsA[NT];            // resolved type-2 operands
  __shared__ int lvl[NT], fsrc[NT];
  __shared__ int schedS[NT], schedL[NT], schedR[NT];
  __shared__ int offs[512], cnt[512], cnt2[512];
  __shared__ unsigned char deadF[NT], liveF[NT], lzero[512];
  __shared__ float a_st[16][256], b_st[16][512];
  __shared__ int changed, smax;

  const float* lb = leafbuf + (size_t)b * 512 * ND;
  float*       ob = outbuf + (size_t)b * NT * ND;

  // ---- load step info + leaf-zero mask ----
  const int4* ib4 = (const int4*)(info + (size_t)b * NT * 4);
  for (int i = tid; i < NT; i += 1024) sinfo4[i] = ib4[i];
  if (tid < 512) lzero[tid] = 1;
  if (tid == 0) smax = 0;
  __syncthreads();
  if (tid < NL) {
    int row = lcid[((size_t)b * NL + tid) * 2];   // slots unique per batch
    lzero[row] = (cmask[(size_t)b * NL + tid] == 0) ? 1 : 0;
  }
  __syncthreads();

  // ---- last-writer scan (broadcast reads; one thread per step) ----
  const int t = tid;
  int4 m1 = {0, 0, 0, 0};
  if (t < NT) m1 = sinfo4[t];
  int l1 = -1, r1 = -1, f1 = -1;
  const int prow = 512 + t;
  for (int tp = 0; tp < NT; ++tp) {
    int4 wi = sinfo4[tp];
    if (wi.x > 0) {   // type-1/2 write row wi.y (in [512,1023))
      if (t < NT && tp < t) { if (wi.y == m1.z) l1 = tp; if (wi.y == m1.w) r1 = tp; }
      if (wi.y == prow) f1 = tp;
    }
  }
  if (t < NT) { lwl[t] = l1; lwr[t] = r1; fwr[t] = f1; }
  __syncthreads();

  // ---- type-1 chain collapse via pointer jumping ----
  if (t < NT) {
    int v;
    if (m1.x == 2) v = SLOTC + t;
    else if (m1.x == 1) {
      if (m1.z < 512) v = m1.z;
      else v = (l1 >= 0) ? (STEPC + l1) : SRC_ZERO;
    } else v = SRC_ZERO;
    ptr_[t] = v;
  }
  __syncthreads();
  for (int it = 0; it < 10; ++it) {   // 2^10 covers any chain length <= 511
    int v = 0;
    if (t < NT) { v = ptr_[t]; if (v >= STEPC) v = ptr_[v - STEPC]; }
    __syncthreads();
    if (t < NT) ptr_[t] = v;
    __syncthreads();
  }

  // ---- resolve type-2 operands + final row sources ----
  auto normv = [&](int v) -> int {   // masked-out leaf row == zero vector
    if (v >= 0 && v < 512 && lzero[v]) return SRC_ZERO;
    return v;
  };
  auto collapseW = [&](int wstep) -> int {
    int v = (sinfo4[wstep].x == 2) ? (SLOTC + wstep) : ptr_[wstep];
    return normv(v);
  };
  if (t < NT) {
    if (m1.x == 2) {
      int a = (m1.z < 512) ? normv(m1.z) : ((l1 >= 0) ? collapseW(l1) : SRC_ZERO);
      int c = (m1.w < 512) ? normv(m1.w) : ((r1 >= 0) ? collapseW(r1) : SRC_ZERO);
      lsA[t] = a; rsA[t] = c;
      deadF[t] = (a == SRC_ZERO || c == SRC_ZERO) ? 1 : 0;
    } else {
      deadF[t] = 0;
    }
    liveF[t] = 0;
    fsrc[t] = (f1 >= 0) ? collapseW(f1) : SRC_ZERO;
  }
  __syncthreads();

  // ---- zero propagation fixpoint (corr with zero operand == exact zero) ----
  for (int rounds = 0; rounds < NT; ++rounds) {
    if (tid == 0) changed = 0;
    __syncthreads();
    if (t < NT && m1.x == 2 && !deadF[t]) {
      int a = lsA[t], c = rsA[t];
      if (a >= SLOTC && deadF[a - SLOTC]) { a = SRC_ZERO; lsA[t] = a; }
      if (c >= SLOTC && deadF[c - SLOTC]) { c = SRC_ZERO; rsA[t] = c; }
      if (a == SRC_ZERO || c == SRC_ZERO) { deadF[t] = 1; changed = 1; }
    }
    __syncthreads();
    if (!changed) break;
    __syncthreads();
  }

  // ---- backward liveness (skip ops whose output is never read) ----
  if (t < NT) {
    int f = fsrc[t];
    if (f >= SLOTC && deadF[f - SLOTC]) { f = SRC_ZERO; fsrc[t] = f; }
    if (f >= SLOTC) liveF[f - SLOTC] = 1;
  }
  __syncthreads();
  for (int rounds = 0; rounds < NT; ++rounds) {
    if (tid == 0) changed = 0;
    __syncthreads();
    if (t < NT && m1.x == 2 && liveF[t] && !deadF[t]) {
      int a = lsA[t], c = rsA[t];
      if (a >= SLOTC && !liveF[a - SLOTC]) { liveF[a - SLOTC] = 1; changed = 1; }
      if (c >= SLOTC && !liveF[c - SLOTC]) { liveF[c - SLOTC] = 1; changed = 1; }
    }
    __syncthreads();
    if (!changed) break;
    __syncthreads();
  }

  const bool isLive = (t < NT && m1.x == 2 && liveF[t] && !deadF[t]);

  // ---- ASAP levels via monotone fixpoint ----
  if (t < NT) lvl[t] = 0;
  __syncthreads();
  for (int rounds = 0; rounds < NT; ++rounds) {
    if (tid == 0) changed = 0;
    __syncthreads();
    if (isLive) {
      int nl = 1, a = lsA[t], c = rsA[t];
      if (a >= SLOTC) { int dl = lvl[a - SLOTC] + 1; if (dl > nl) nl = dl; }
      if (c >= SLOTC) { int dl = lvl[c - SLOTC] + 1; if (dl > nl) nl = dl; }
      if (nl > lvl[t]) { lvl[t] = nl; changed = 1; }
    }
    __syncthreads();
    if (!changed) break;
    __syncthreads();
  }
  if (isLive) atomicMax(&smax, lvl[t]);

  // ---- bucket ops by level ----
  if (tid < 512) { cnt[tid] = 0; cnt2[tid] = 0; }
  __syncthreads();
  if (isLive) atomicAdd(&cnt[lvl[t]], 1);
  __syncthreads();
  if (tid < 512) offs[tid] = cnt[tid];
  __syncthreads();
  for (int k = 1; k < 512; k <<= 1) {   // inclusive prefix over levels
    int v = 0;
    if (tid < 512) { v = offs[tid]; if (tid >= k) v += offs[tid - k]; }
    __syncthreads();
    if (tid < 512) offs[tid] = v;
    __syncthreads();
  }
  if (isLive) {
    int d = lvl[t];
    int pos = offs[d - 1] + atomicAdd(&cnt2[d], 1);   // d>=1 always
    schedS[pos] = t; schedL[pos] = lsA[t]; schedR[pos] = rsA[t];
  }
  __syncthreads();

  // ---- level-parallel execution: one op per wave ----
  const int maxd = smax;
  for (int d = 1; d <= maxd; ++d) {
    const int base = offs[d - 1];
    const int nops = cnt[d];
    const int nch  = (nops + 15) >> 4;
    for (int ch = 0; ch < nch; ++ch) {
      int rel = ch * 16 + wav;
      if (rel < nops) {           // wave-uniform predicate (depends on wav only)
        int my = base + rel;
        int tt = schedS[my], ls = schedL[my], rs = schedR[my];
        const float* pa = (ls < 512) ? lb + (size_t)ls * ND
                                     : ob + (size_t)(ls - SLOTC) * ND;
        const float* pb = (rs < 512) ? lb + (size_t)rs * ND
                                     : ob + (size_t)(rs - SLOTC) * ND;
        float4 av = ((const float4*)pa)[lane];
        float4 bv = ((const float4*)pb)[lane];
        ((float4*)a_st[wav])[lane] = av;
        ((float4*)b_st[wav])[lane]      = bv;
        ((float4*)b_st[wav])[lane + 64] = bv;   // doubled for mod-256 window
        const float4* a4 = (const float4*)a_st[wav];
        const float4* b4 = (const float4*)b_st[wav];
        // c[4*lane+r] = sum_j a[j] * b[(j + 4*lane + r) & 255]
        float c0 = 0.f, c1 = 0.f, c2 = 0.f, c3 = 0.f;
        float4 B0 = b4[lane];
#pragma unroll 8
        for (int i = 0; i < 64; ++i) {
          float4 A  = a4[i];             // uniform -> LDS broadcast
          float4 B1 = b4[lane + i + 1];  // rolling window (stride-16B, conflict-free)
          c0 += A.x * B0.x + A.y * B0.y + A.z * B0.z + A.w * B0.w;
          c1 += A.x * B0.y + A.y * B0.z + A.z * B0.w + A.w * B1.x;
          c2 += A.x * B0.z + A.y * B0.w + A.z * B1.x + A.w * B1.y;
          c3 += A.x * B0.w + A.y * B1.x + A.z * B1.y + A.w * B1.z;
          B0 = B1;
        }
        float ss = c0 * c0 + c1 * c1 + c2 * c2 + c3 * c3;
#pragma unroll
        for (int off = 32; off > 0; off >>= 1) ss += __shfl_down(ss, off, 64);
        ss = __shfl(ss, 0, 64);
        float inv = 1.f / (sqrtf(ss) + EPSF);
        float4 res;
        res.x = c0 * inv; res.y = c1 * inv; res.z = c2 * inv; res.w = c3 * inv;
        ((float4*)(ob + (size_t)tt * ND))[lane] = res;
      }
      // no intra-level barrier: staging is wave-private, deps are cross-level
    }
    __syncthreads();   // level boundary: drains stores; next level reads hit L2
  }

  // ---- export final-row sources for the gather kernel ----
  for (int i = tid; i < NT; i += 1024) fsrcG[b * NT + i] = fsrc[i];
}

// ---------------------------------------------------------------------------
// Phase 2b: full-grid gather of parent rows -> vecb (bf16). One wave per row.
// (round-0 verbatim)
// ---------------------------------------------------------------------------
__global__ void __launch_bounds__(256) gather_rows(
    const int* __restrict__ fsrcG, const float* __restrict__ leafbuf,
    const float* __restrict__ outbuf, unsigned short* __restrict__ vecb) {
  int rid  = blockIdx.x * 4 + (threadIdx.x >> 6);   // b*NT + idx  (exact grid)
  int lane = threadIdx.x & 63;
  int b    = rid / NT;
  int idx  = rid - b * NT;
  int s    = fsrcG[rid];
  float4 v = {0.f, 0.f, 0.f, 0.f};
  if (s >= 0) {
    const float* src = (s < 512)
        ? (leafbuf + ((size_t)b * 512 + s) * ND)
        : (outbuf + ((size_t)b * NT + (s - SLOTC)) * ND);
    v = ((const float4*)src)[lane];
  }
  uint2 pk;
  pk.x = (unsigned)f2bf(v.x) | ((unsigned)f2bf(v.y) << 16);
  pk.y = (unsigned)f2bf(v.z) | ((unsigned)f2bf(v.w) << 16);
  ((uint2*)(vecb + ((size_t)b * NN + 512 + idx) * ND))[lane] = pk;
}

// ---------------------------------------------------------------------------
// Phase 3: out[m][c] = sum_k A[m][k]*W[c][k] + bias[c]  (A: 130944x256 bf16,
// W: 512x256 bf16 zero-padded). 128x128 tile, BK=64, global_load_lds w=16,
// mfma_f32_16x16x32_bf16. Grid (4, 1023).
//
// Bank-conflict fix (rule #21, passed round 2): LDS dest linear; SOURCE chunk
// pre-swizzled (ch ^= row&7); fragment read XORs the same involution.
//
// Coalesced epilogue: per-wave transpose of the 16-row strip through a
// private LDS buffer (union with As/Ws, dead after the K loop); each store
// instruction then covers 64 consecutive floats (256B run) instead of four
// 64B segments at 2044B stride. Same-wave DS ordering -> no barrier needed.
// ---------------------------------------------------------------------------
union GemmSh {
  struct { short As[128 * 64]; short Ws[128 * 64]; } s;   // 32 KB
  float epi[4][16][65];                                   // 16.6 KB (padded)
};

__global__ void __launch_bounds__(256) gemm_kernel(
    const short* __restrict__ A, const short* __restrict__ W,
    const float* __restrict__ bias, float* __restrict__ out) {
  __shared__ GemmSh sh;
  int tid  = threadIdx.x;
  int lane = tid & 63;
  int w    = tid >> 6;
  int c0   = blockIdx.x * 128;
  int m0   = blockIdx.y * 128;
  int wm   = (w & 1) * 64;
  int wc   = (w >> 1) * 64;
  int frow = lane & 15;
  int quad = lane >> 4;
  f32x4 acc[4][4];
#pragma unroll
  for (int i = 0; i < 4; ++i)
#pragma unroll
    for (int j = 0; j < 4; ++j) acc[i][j] = (f32x4){0.f, 0.f, 0.f, 0.f};

  for (int k0 = 0; k0 < ND; k0 += 64) {
#pragma unroll
    for (int i = 0; i < 4; ++i) {
      int idx = i * 256 + tid;
      int row = idx >> 3;
      int ch  = idx & 7;
      int chs = ch ^ (row & 7);   // pre-swizzled source chunk
      const short* ga = A + (size_t)(m0 + row) * ND + k0 + chs * 8;
      const short* gw = W + (size_t)(c0 + row) * ND + k0 + chs * 8;
      __builtin_amdgcn_global_load_lds(
          (const __attribute__((address_space(1))) void*)ga,
          (__attribute__((address_space(3))) void*)(sh.s.As + idx * 8), 16, 0, 0);
      __builtin_amdgcn_global_load_lds(
          (const __attribute__((address_space(1))) void*)gw,
          (__attribute__((address_space(3))) void*)(sh.s.Ws + idx * 8), 16, 0, 0);
    }
    __syncthreads();
#pragma unroll
    for (int ks = 0; ks < 2; ++ks) {
      short8 af[4], wf[4];
#pragma unroll
      for (int mi = 0; mi < 4; ++mi) {
        int r = wm + mi * 16 + frow;
        int cc = (ks * 4 + quad) ^ (r & 7);
        af[mi] = *(const short8*)(sh.s.As + r * 64 + cc * 8);
      }
#pragma unroll
      for (int ci = 0; ci < 4; ++ci) {
        int r = wc + ci * 16 + frow;
        int cc = (ks * 4 + quad) ^ (r & 7);
        wf[ci] = *(const short8*)(sh.s.Ws + r * 64 + cc * 8);
      }
#pragma unroll
      for (int mi = 0; mi < 4; ++mi)
#pragma unroll
        for (int ci = 0; ci < 4; ++ci)
          acc[mi][ci] = __builtin_amdgcn_mfma_f32_16x16x32_bf16(
              af[mi], wf[ci], acc[mi][ci], 0, 0, 0);
    }
    __syncthreads();
  }

  // ---- coalesced epilogue: per-wave 16x64 transpose through LDS ----
  // All waves have passed the final barrier (LDS reads drained), and each
  // wave touches only epi[w] -> no further barriers needed.
  int colg = c0 + wc + lane;                       // this lane's output column
  float bv = (colg < NC) ? bias[colg] : 0.f;
#pragma unroll
  for (int mi = 0; mi < 4; ++mi) {
#pragma unroll
    for (int ci = 0; ci < 4; ++ci)
#pragma unroll
      for (int r = 0; r < 4; ++r)
        sh.epi[w][quad * 4 + r][ci * 16 + frow] = acc[mi][ci][r];
    // same-wave DS in-order: the reads below see the writes above
    if (colg < NC) {
      int mrow = m0 + wm + mi * 16;
#pragma unroll
      for (int rr = 0; rr < 16; ++rr)
        out[(size_t)(mrow + rr) * NC + colg] = sh.epi[w][rr][lane] + bv;
    }
  }
}

// ---------------------------------------------------------------------------
// Workspace layout (201,392,128 bytes — unchanged):
//   [0)           leafbuf fp32 [B][512][D]  =  67,108,864 B
//   [67108864)    outbuf  fp32 [B][511][D]  =  66,977,792 B
//   [134086656)   vecb    bf16 [B][1023][D] =  67,043,328 B
//   [201129984)   wb      bf16 [512][D]     =     262,144 B
// fsrc (128*511 ints) staged in d_out; gather reads it, gemm overwrites.
// ---------------------------------------------------------------------------
extern "C" void kernel_launch(void* const* d_in, const int* in_sizes, int n_in,
                              void* d_out, int out_size, void* d_ws, size_t ws_size,
                              hipStream_t stream) {
  const int*   lcid  = (const int*)d_in[1];
  const int*   cmask = (const int*)d_in[2];
  const int*   cinfo = (const int*)d_in[3];
  const float* emb   = (const float*)d_in[4];
  const float* lw    = (const float*)d_in[5];
  const float* lbias = (const float*)d_in[6];
  float*       out   = (float*)d_out;

  char* ws = (char*)d_ws;
  float*          leafbuf = (float*)ws;
  float*          outbuf  = (float*)(ws + 67108864);
  unsigned short* vecb    = (unsigned short*)(ws + 134086656);
  unsigned short* wb      = (unsigned short*)(ws + 201129984);
  int*            fsrcG   = (int*)d_out;   // staged; gemm overwrites all of d_out

  embed_scatter<<<16448, 256, 0, stream>>>(lcid, cmask, emb, lw,
                                           leafbuf, vecb, wb);
  compose_kernel<<<NB, 1024, 0, stream>>>(cinfo, lcid, cmask, leafbuf,
                                          outbuf, fsrcG);
  gather_rows<<<NB * NT / 4, 256, 0, stream>>>(fsrcG, leafbuf, outbuf, vecb);
  gemm_kernel<<<dim3(4, 1023), 256, 0, stream>>>(
      (const short*)vecb, (const short*)wb, lbias, out);
}

// Round 6
// 520.608 us; speedup vs baseline: 1.3067x; 1.0747x over previous
//
#include <hip/hip_runtime.h>

// Problem constants (match reference setup_inputs)
#define NB 128
#define NL 512
#define NN 1023
#define NT 511
#define ND 256
#define NC 511
#define EPSF 1e-6f

// Source encoding:
//   SRC_ZERO          -> zero vector
//   0..511            -> leaf row r (leafbuf)
//   SLOTC + t         -> output slot of type-2 step t (outbuf)
//   STEPC + t         -> unresolved reference to writer step t (resolution only)
#define SRC_ZERO (-1)
#define SLOTC 4096
#define STEPC 8192

typedef __attribute__((ext_vector_type(8))) short short8;   // 8 x bf16
typedef __attribute__((ext_vector_type(4))) float f32x4;    // MFMA accumulator
typedef __attribute__((ext_vector_type(2))) float f32x2;    // packed fp32 pair

__device__ __forceinline__ unsigned short f2bf(float f) {
  unsigned u = __builtin_bit_cast(unsigned, f);
  u += 0x7FFFu + ((u >> 16) & 1u);   // round-to-nearest-even
  return (unsigned short)(u >> 16);
}

// ---------------------------------------------------------------------------
// Phase 1: embed (normalize emb rows -> leafbuf fp32 + vecb bf16) and cvt_w,
// merged into one launch. blocks [0,16384): embed (4 rows/block);
// blocks [16384,16448): lin_weight -> bf16 padded to 512 rows.
// ---------------------------------------------------------------------------
__global__ void __launch_bounds__(256) embed_scatter(
    const int* __restrict__ lcid, const int* __restrict__ cmask,
    const float* __restrict__ emb, const float* __restrict__ lw,
    float* __restrict__ leafbuf, unsigned short* __restrict__ vecb,
    unsigned short* __restrict__ wb) {
  if (blockIdx.x >= 16384) {          // ---- cvt_w ----
    int i   = (blockIdx.x - 16384) * 256 + threadIdx.x;   // [0,16384)
    int row = i >> 5;
    uint4 r = {0u, 0u, 0u, 0u};
    if (row < NC) {
      const float4* v4 = (const float4*)lw;
      float4 x = v4[2 * i], y = v4[2 * i + 1];
      r.x = (unsigned)f2bf(x.x) | ((unsigned)f2bf(x.y) << 16);
      r.y = (unsigned)f2bf(x.z) | ((unsigned)f2bf(x.w) << 16);
      r.z = (unsigned)f2bf(y.x) | ((unsigned)f2bf(y.y) << 16);
      r.w = (unsigned)f2bf(y.z) | ((unsigned)f2bf(y.w) << 16);
    }
    ((uint4*)wb)[i] = r;
    return;
  }
  int rid  = blockIdx.x * 4 + (threadIdx.x >> 6);   // b*NL + l
  int lane = threadIdx.x & 63;
  int slot = lcid[2 * rid];
  int vid  = lcid[2 * rid + 1];
  int msk  = cmask[rid];
  int b    = rid >> 9;                               // / NL
  float4 v = {0.f, 0.f, 0.f, 0.f};
  if (msk) v = ((const float4*)(emb + (size_t)vid * ND))[lane];
  float ss = v.x * v.x + v.y * v.y + v.z * v.z + v.w * v.w;
#pragma unroll
  for (int off = 32; off > 0; off >>= 1) ss += __shfl_down(ss, off, 64);
  ss = __shfl(ss, 0, 64);
  float inv = 1.0f / (sqrtf(ss) + EPSF);   // msk==0: v=0 -> o=0 (no NaN)
  float4 o;
  o.x = v.x * inv; o.y = v.y * inv; o.z = v.z * inv; o.w = v.w * inv;
  ((float4*)(leafbuf + ((size_t)b * 512 + slot) * ND))[lane] = o;
  uint2 pk;
  pk.x = (unsigned)f2bf(o.x) | ((unsigned)f2bf(o.y) << 16);
  pk.y = (unsigned)f2bf(o.z) | ((unsigned)f2bf(o.w) << 16);
  ((uint2*)(vecb + ((size_t)b * NN + slot) * ND))[lane] = pk;
}

// ---------------------------------------------------------------------------
// Phase 2: compose. One block (1024 threads = 16 waves) per batch.
// Resolution = round-0 proven code. Exec = one op per wave (proven barrier
// structure) with a PACKED inner loop: a +1-shifted doubled copy of b lets
// all four per-lane outputs use aligned float2 pairs -> v_pk_fma_f32
// (8 packed FMA + 3 ds_read_b128 per 4 j's, vs 16 scalar FMA + 2 reads).
// Only the fp32 summation order changes (even/odd-j partials).
// ---------------------------------------------------------------------------
__global__ void __launch_bounds__(1024) compose_kernel(
    const int* __restrict__ info, const int* __restrict__ lcid,
    const int* __restrict__ cmask, const float* __restrict__ leafbuf,
    float* __restrict__ outbuf, int* __restrict__ fsrcG) {
  const int b    = blockIdx.x;
  const int tid  = threadIdx.x;
  const int lane = tid & 63;
  const int wav  = tid >> 6;

  __shared__ int4 sinfo4[NT];                 // (ctype, parent, lchild, rchild)
  __shared__ int ptr_[NT];                    // type-1 chain terminal
  __shared__ int lsA[NT], rsA[NT];            // resolved type-2 operands
  __shared__ int lvl[NT], fsrc[NT];
  __shared__ int schedS[NT], schedL[NT], schedR[NT];
  __shared__ int offs[512], cnt[512], cnt2[512];
  __shared__ unsigned char deadF[NT], liveF[NT], lzero[512];
  __shared__ float a_st[16][256];
  __shared__ float b_st[16][512];             // doubled b
  __shared__ float s_st[16][512];             // doubled b shifted by +1
  __shared__ int changed, smax;

  const float* lb = leafbuf + (size_t)b * 512 * ND;
  float*       ob = outbuf + (size_t)b * NT * ND;

  // ---- load step info + leaf-zero mask ----
  const int4* ib4 = (const int4*)(info + (size_t)b * NT * 4);
  for (int i = tid; i < NT; i += 1024) sinfo4[i] = ib4[i];
  if (tid < 512) lzero[tid] = 1;
  if (tid == 0) smax = 0;
  __syncthreads();
  if (tid < NL) {
    int row = lcid[((size_t)b * NL + tid) * 2];   // slots unique per batch
    lzero[row] = (cmask[(size_t)b * NL + tid] == 0) ? 1 : 0;
  }
  __syncthreads();

  // ---- last-writer scan (broadcast reads; one thread per step) ----
  const int t = tid;
  int4 m1 = {0, 0, 0, 0};
  if (t < NT) m1 = sinfo4[t];
  int l1 = -1, r1 = -1, f1 = -1;
  const int prow = 512 + t;
  for (int tp = 0; tp < NT; ++tp) {
    int4 wi = sinfo4[tp];
    if (wi.x > 0) {   // type-1/2 write row wi.y (in [512,1023))
      if (t < NT && tp < t) { if (wi.y == m1.z) l1 = tp; if (wi.y == m1.w) r1 = tp; }
      if (wi.y == prow) f1 = tp;
    }
  }
  __syncthreads();

  // ---- type-1 chain collapse via pointer jumping ----
  if (t < NT) {
    int v;
    if (m1.x == 2) v = SLOTC + t;
    else if (m1.x == 1) {
      if (m1.z < 512) v = m1.z;
      else v = (l1 >= 0) ? (STEPC + l1) : SRC_ZERO;
    } else v = SRC_ZERO;
    ptr_[t] = v;
  }
  __syncthreads();
  for (int it = 0; it < 10; ++it) {   // 2^10 covers any chain length <= 511
    int v = 0;
    if (t < NT) { v = ptr_[t]; if (v >= STEPC) v = ptr_[v - STEPC]; }
    __syncthreads();
    if (t < NT) ptr_[t] = v;
    __syncthreads();
  }

  // ---- resolve type-2 operands + final row sources ----
  auto normv = [&](int v) -> int {   // masked-out leaf row == zero vector
    if (v >= 0 && v < 512 && lzero[v]) return SRC_ZERO;
    return v;
  };
  auto collapseW = [&](int wstep) -> int {
    int v = (sinfo4[wstep].x == 2) ? (SLOTC + wstep) : ptr_[wstep];
    return normv(v);
  };
  if (t < NT) {
    if (m1.x == 2) {
      int a = (m1.z < 512) ? normv(m1.z) : ((l1 >= 0) ? collapseW(l1) : SRC_ZERO);
      int c = (m1.w < 512) ? normv(m1.w) : ((r1 >= 0) ? collapseW(r1) : SRC_ZERO);
      lsA[t] = a; rsA[t] = c;
      deadF[t] = (a == SRC_ZERO || c == SRC_ZERO) ? 1 : 0;
    } else {
      deadF[t] = 0;
    }
    liveF[t] = 0;
    fsrc[t] = (f1 >= 0) ? collapseW(f1) : SRC_ZERO;
  }
  __syncthreads();

  // ---- zero propagation fixpoint (corr with zero operand == exact zero) ----
  for (int rounds = 0; rounds < NT; ++rounds) {
    if (tid == 0) changed = 0;
    __syncthreads();
    if (t < NT && m1.x == 2 && !deadF[t]) {
      int a = lsA[t], c = rsA[t];
      if (a >= SLOTC && deadF[a - SLOTC]) { a = SRC_ZERO; lsA[t] = a; }
      if (c >= SLOTC && deadF[c - SLOTC]) { c = SRC_ZERO; rsA[t] = c; }
      if (a == SRC_ZERO || c == SRC_ZERO) { deadF[t] = 1; changed = 1; }
    }
    __syncthreads();
    if (!changed) break;
    __syncthreads();
  }

  // ---- backward liveness (skip ops whose output is never read) ----
  if (t < NT) {
    int f = fsrc[t];
    if (f >= SLOTC && deadF[f - SLOTC]) { f = SRC_ZERO; fsrc[t] = f; }
    if (f >= SLOTC) liveF[f - SLOTC] = 1;
  }
  __syncthreads();
  for (int rounds = 0; rounds < NT; ++rounds) {
    if (tid == 0) changed = 0;
    __syncthreads();
    if (t < NT && m1.x == 2 && liveF[t] && !deadF[t]) {
      int a = lsA[t], c = rsA[t];
      if (a >= SLOTC && !liveF[a - SLOTC]) { liveF[a - SLOTC] = 1; changed = 1; }
      if (c >= SLOTC && !liveF[c - SLOTC]) { liveF[c - SLOTC] = 1; changed = 1; }
    }
    __syncthreads();
    if (!changed) break;
    __syncthreads();
  }

  const bool isLive = (t < NT && m1.x == 2 && liveF[t] && !deadF[t]);

  // ---- ASAP levels via monotone fixpoint ----
  if (t < NT) lvl[t] = 0;
  __syncthreads();
  for (int rounds = 0; rounds < NT; ++rounds) {
    if (tid == 0) changed = 0;
    __syncthreads();
    if (isLive) {
      int nl = 1, a = lsA[t], c = rsA[t];
      if (a >= SLOTC) { int dl = lvl[a - SLOTC] + 1; if (dl > nl) nl = dl; }
      if (c >= SLOTC) { int dl = lvl[c - SLOTC] + 1; if (dl > nl) nl = dl; }
      if (nl > lvl[t]) { lvl[t] = nl; changed = 1; }
    }
    __syncthreads();
    if (!changed) break;
    __syncthreads();
  }
  if (isLive) atomicMax(&smax, lvl[t]);

  // ---- bucket ops by level ----
  if (tid < 512) { cnt[tid] = 0; cnt2[tid] = 0; }
  __syncthreads();
  if (isLive) atomicAdd(&cnt[lvl[t]], 1);
  __syncthreads();
  if (tid < 512) offs[tid] = cnt[tid];
  __syncthreads();
  for (int k = 1; k < 512; k <<= 1) {   // inclusive prefix over levels
    int v = 0;
    if (tid < 512) { v = offs[tid]; if (tid >= k) v += offs[tid - k]; }
    __syncthreads();
    if (tid < 512) offs[tid] = v;
    __syncthreads();
  }
  if (isLive) {
    int d = lvl[t];
    int pos = offs[d - 1] + atomicAdd(&cnt2[d], 1);   // d>=1 always
    schedS[pos] = t; schedL[pos] = lsA[t]; schedR[pos] = rsA[t];
  }
  __syncthreads();

  // ---- level-parallel execution: one op per wave, packed inner loop ----
  const int maxd = smax;
  for (int d = 1; d <= maxd; ++d) {
    const int base = offs[d - 1];
    const int nops = cnt[d];
    const int nch  = (nops + 15) >> 4;
    for (int ch = 0; ch < nch; ++ch) {
      int rel = ch * 16 + wav;
      if (rel < nops) {           // wave-uniform predicate (depends on wav only)
        int my = base + rel;
        int tt = schedS[my], ls = schedL[my], rs = schedR[my];
        const float* pa = (ls < 512) ? lb + (size_t)ls * ND
                                     : ob + (size_t)(ls - SLOTC) * ND;
        const float* pb = (rs < 512) ? lb + (size_t)rs * ND
                                     : ob + (size_t)(rs - SLOTC) * ND;
        float4 av = ((const float4*)pa)[lane];
        float4 bv = ((const float4*)pb)[lane];
        // shifted copy: s[x] = b[(x+1) & 255]; per lane s[4l..4l+3] =
        // (b[4l+1], b[4l+2], b[4l+3], b[4(l+1)]) — last via lane shuffle
        float nx = __shfl(bv.x, (lane + 1) & 63, 64);
        float4 sv = {bv.y, bv.z, bv.w, nx};
        ((float4*)a_st[wav])[lane]      = av;
        ((float4*)b_st[wav])[lane]      = bv;
        ((float4*)b_st[wav])[lane + 64] = bv;   // doubled for mod-256 window
        ((float4*)s_st[wav])[lane]      = sv;
        ((float4*)s_st[wav])[lane + 64] = sv;
        const float4* a4 = (const float4*)a_st[wav];
        const float4* b4 = (const float4*)b_st[wav];
        const float4* s4 = (const float4*)s_st[wav];
        // c[4*lane+r] = sum_j a[j] * b[(j + 4*lane + r) & 255]
        // even/odd-j packed partials; all pairs 8B-aligned:
        //  c0: (A.xy·B0.xy)+(A.zw·B0.zw)   c1: (A.xy·S0.xy)+(A.zw·S0.zw)
        //  c2: (A.xy·B0.zw)+(A.zw·B1.xy)   c3: (A.xy·S0.zw)+(A.zw·S1.xy)
        f32x2 q0 = {0.f, 0.f}, q1 = {0.f, 0.f}, q2 = {0.f, 0.f}, q3 = {0.f, 0.f};
        float4 B0 = b4[lane];
        float4 S0 = s4[lane];
#pragma unroll 8
        for (int i = 0; i < 64; ++i) {
          float4 A  = a4[i];             // uniform -> LDS broadcast
          float4 B1 = b4[lane + i + 1];  // rolling windows, conflict-free
          float4 S1 = s4[lane + i + 1];
          f32x2 Axy = {A.x, A.y},  Azw = {A.z, A.w};
          f32x2 Bxy = {B0.x, B0.y}, Bzw = {B0.z, B0.w};
          f32x2 Sxy = {S0.x, S0.y}, Szw = {S0.z, S0.w};
          f32x2 B1xy = {B1.x, B1.y}, S1xy = {S1.x, S1.y};
          q0 += Axy * Bxy;  q0 += Azw * Bzw;
          q1 += Axy * Sxy;  q1 += Azw * Szw;
          q2 += Axy * Bzw;  q2 += Azw * B1xy;
          q3 += Axy * Szw;  q3 += Azw * S1xy;
          B0 = B1; S0 = S1;
        }
        float c0 = q0.x + q0.y, c1 = q1.x + q1.y;
        float c2 = q2.x + q2.y, c3 = q3.x + q3.y;
        float ss = c0 * c0 + c1 * c1 + c2 * c2 + c3 * c3;
#pragma unroll
        for (int off = 32; off > 0; off >>= 1) ss += __shfl_down(ss, off, 64);
        ss = __shfl(ss, 0, 64);
        float inv = 1.f / (sqrtf(ss) + EPSF);
        float4 res;
        res.x = c0 * inv; res.y = c1 * inv; res.z = c2 * inv; res.w = c3 * inv;
        ((float4*)(ob + (size_t)tt * ND))[lane] = res;
      }
      // no intra-level barrier: staging is wave-private, deps are cross-level
    }
    __syncthreads();   // level boundary: drains stores; next level reads hit L2
  }

  // ---- export final-row sources for the gather kernel ----
  for (int i = tid; i < NT; i += 1024) fsrcG[b * NT + i] = fsrc[i];
}

// ---------------------------------------------------------------------------
// Phase 2b: full-grid gather of parent rows -> vecb (bf16). One wave per row.
// ---------------------------------------------------------------------------
__global__ void __launch_bounds__(256) gather_rows(
    const int* __restrict__ fsrcG, const float* __restrict__ leafbuf,
    const float* __restrict__ outbuf, unsigned short* __restrict__ vecb) {
  int rid  = blockIdx.x * 4 + (threadIdx.x >> 6);   // b*NT + idx  (exact grid)
  int lane = threadIdx.x & 63;
  int b    = rid / NT;
  int idx  = rid - b * NT;
  int s    = fsrcG[rid];
  float4 v = {0.f, 0.f, 0.f, 0.f};
  if (s >= 0) {
    const float* src = (s < 512)
        ? (leafbuf + ((size_t)b * 512 + s) * ND)
        : (outbuf + ((size_t)b * NT + (s - SLOTC)) * ND);
    v = ((const float4*)src)[lane];
  }
  uint2 pk;
  pk.x = (unsigned)f2bf(v.x) | ((unsigned)f2bf(v.y) << 16);
  pk.y = (unsigned)f2bf(v.z) | ((unsigned)f2bf(v.w) << 16);
  ((uint2*)(vecb + ((size_t)b * NN + 512 + idx) * ND))[lane] = pk;
}

// ---------------------------------------------------------------------------
// Phase 3: out[m][c] = sum_k A[m][k]*W[c][k] + bias[c]  (A: 130944x256 bf16,
// W: 512x256 bf16 zero-padded). 128x128 tile, BK=64, global_load_lds w=16,
// mfma_f32_16x16x32_bf16.
//
// XCD-grouped block remap (NEW): flat grid 4096; i -> q=i>>5, t=i&31,
// m=q*8+(t&7), c=t>>3 (skip m==1023). The 4 col-blocks sharing an A-tile get
// identical i%8 == m&7 -> SAME XCD, <=24 dispatches apart -> A-tile served
// from that XCD's L2, fetched from HBM once (was 4x: consecutive blockIdx
// round-robins XCDs, so the old (4,1023) grid put siblings on 4 XCDs).
//
// Bank-conflict fix (rule #21, passed round 2): LDS dest linear; SOURCE chunk
// pre-swizzled (ch ^= row&7); fragment read XORs the same involution.
// Coalesced epilogue via per-wave LDS transpose (passed round 5).
// ---------------------------------------------------------------------------
union GemmSh {
  struct { short As[128 * 64]; short Ws[128 * 64]; } s;   // 32 KB
  float epi[4][16][65];                                   // 16.6 KB (padded)
};

__global__ void __launch_bounds__(256) gemm_kernel(
    const short* __restrict__ A, const short* __restrict__ W,
    const float* __restrict__ bias, float* __restrict__ out) {
  __shared__ GemmSh sh;
  int i = blockIdx.x;
  int m = (i >> 5) * 8 + (i & 7);     // m-tile [0,1024)
  int c = (i >> 3) & 3;               // col-tile [0,4)
  if (m >= 1023) return;
  int tid  = threadIdx.x;
  int lane = tid & 63;
  int w    = tid >> 6;
  int c0   = c * 128;
  int m0   = m * 128;
  int wm   = (w & 1) * 64;
  int wc   = (w >> 1) * 64;
  int frow = lane & 15;
  int quad = lane >> 4;
  f32x4 acc[4][4];
#pragma unroll
  for (int a = 0; a < 4; ++a)
#pragma unroll
    for (int j = 0; j < 4; ++j) acc[a][j] = (f32x4){0.f, 0.f, 0.f, 0.f};

  for (int k0 = 0; k0 < ND; k0 += 64) {
#pragma unroll
    for (int a = 0; a < 4; ++a) {
      int idx = a * 256 + tid;
      int row = idx >> 3;
      int ch  = idx & 7;
      int chs = ch ^ (row & 7);   // pre-swizzled source chunk
      const short* ga = A + (size_t)(m0 + row) * ND + k0 + chs * 8;
      const short* gw = W + (size_t)(c0 + row) * ND + k0 + chs * 8;
      __builtin_amdgcn_global_load_lds(
          (const __attribute__((address_space(1))) void*)ga,
          (__attribute__((address_space(3))) void*)(sh.s.As + idx * 8), 16, 0, 0);
      __builtin_amdgcn_global_load_lds(
          (const __attribute__((address_space(1))) void*)gw,
          (__attribute__((address_space(3))) void*)(sh.s.Ws + idx * 8), 16, 0, 0);
    }
    __syncthreads();
#pragma unroll
    for (int ks = 0; ks < 2; ++ks) {
      short8 af[4], wf[4];
#pragma unroll
      for (int mi = 0; mi < 4; ++mi) {
        int r = wm + mi * 16 + frow;
        int cc = (ks * 4 + quad) ^ (r & 7);
        af[mi] = *(const short8*)(sh.s.As + r * 64 + cc * 8);
      }
#pragma unroll
      for (int ci = 0; ci < 4; ++ci) {
        int r = wc + ci * 16 + frow;
        int cc = (ks * 4 + quad) ^ (r & 7);
        wf[ci] = *(const short8*)(sh.s.Ws + r * 64 + cc * 8);
      }
#pragma unroll
      for (int mi = 0; mi < 4; ++mi)
#pragma unroll
        for (int ci = 0; ci < 4; ++ci)
          acc[mi][ci] = __builtin_amdgcn_mfma_f32_16x16x32_bf16(
              af[mi], wf[ci], acc[mi][ci], 0, 0, 0);
    }
    __syncthreads();
  }

  // ---- coalesced epilogue: per-wave 16x64 transpose through LDS ----
  int colg = c0 + wc + lane;                       // this lane's output column
  float bv = (colg < NC) ? bias[colg] : 0.f;
#pragma unroll
  for (int mi = 0; mi < 4; ++mi) {
#pragma unroll
    for (int ci = 0; ci < 4; ++ci)
#pragma unroll
      for (int r = 0; r < 4; ++r)
        sh.epi[w][quad * 4 + r][ci * 16 + frow] = acc[mi][ci][r];
    // same-wave DS in-order: the reads below see the writes above
    if (colg < NC) {
      int mrow = m0 + wm + mi * 16;
#pragma unroll
      for (int rr = 0; rr < 16; ++rr)
        out[(size_t)(mrow + rr) * NC + colg] = sh.epi[w][rr][lane] + bv;
    }
  }
}

// ---------------------------------------------------------------------------
// Workspace layout (201,392,128 bytes — unchanged):
//   [0)           leafbuf fp32 [B][512][D]  =  67,108,864 B
//   [67108864)    outbuf  fp32 [B][511][D]  =  66,977,792 B
//   [134086656)   vecb    bf16 [B][1023][D] =  67,043,328 B
//   [201129984)   wb      bf16 [512][D]     =     262,144 B
// fsrc (128*511 ints) staged in d_out; gather reads it, gemm overwrites.
// ---------------------------------------------------------------------------
extern "C" void kernel_launch(void* const* d_in, const int* in_sizes, int n_in,
                              void* d_out, int out_size, void* d_ws, size_t ws_size,
                              hipStream_t stream) {
  const int*   lcid  = (const int*)d_in[1];
  const int*   cmask = (const int*)d_in[2];
  const int*   cinfo = (const int*)d_in[3];
  const float* emb   = (const float*)d_in[4];
  const float* lw    = (const float*)d_in[5];
  const float* lbias = (const float*)d_in[6];
  float*       out   = (float*)d_out;

  char* ws = (char*)d_ws;
  float*          leafbuf = (float*)ws;
  float*          outbuf  = (float*)(ws + 67108864);
  unsigned short* vecb    = (unsigned short*)(ws + 134086656);
  unsigned short* wb      = (unsigned short*)(ws + 201129984);
  int*            fsrcG   = (int*)d_out;   // staged; gemm overwrites all of d_out

  embed_scatter<<<16448, 256, 0, stream>>>(lcid, cmask, emb, lw,
                                           leafbuf, vecb, wb);
  compose_kernel<<<NB, 1024, 0, stream>>>(cinfo, lcid, cmask, leafbuf,
                                          outbuf, fsrcG);
  gather_rows<<<NB * NT / 4, 256, 0, stream>>>(fsrcG, leafbuf, outbuf, vecb);
  gemm_kernel<<<4096, 256, 0, stream>>>(
      (const short*)vecb, (const short*)wb, lbias, out);
}

// Round 8
// 480.647 us; speedup vs baseline: 1.4154x; 1.0831x over previous
//
#include <hip/hip_runtime.h>

// Problem constants (match reference setup_inputs)
#define NB 128
#define NL 512
#define NN 1023
#define NT 511
#define ND 256
#define NC 511
#define EPSF 1e-6f

// Source encoding:
//   SRC_ZERO          -> zero vector
//   0..511            -> leaf row r (leafbuf)
//   SLOTC + t         -> output slot of type-2 step t (outbuf)
//   STEPC + t         -> unresolved reference to writer step t (resolution only)
#define SRC_ZERO (-1)
#define SLOTC 4096
#define STEPC 8192

typedef __attribute__((ext_vector_type(8))) short short8;   // 8 x bf16
typedef __attribute__((ext_vector_type(4))) float f32x4;    // MFMA accumulator
typedef __attribute__((ext_vector_type(2))) float f32x2;    // packed fp32 pair

__device__ __forceinline__ unsigned short f2bf(float f) {
  unsigned u = __builtin_bit_cast(unsigned, f);
  u += 0x7FFFu + ((u >> 16) & 1u);   // round-to-nearest-even
  return (unsigned short)(u >> 16);
}

// ---------------------------------------------------------------------------
// Phase 1: embed (normalize emb rows -> leafbuf fp32 + vecb bf16) and cvt_w,
// merged into one launch. blocks [0,16384): embed (4 rows/block);
// blocks [16384,16448): lin_weight -> bf16 padded to 512 rows.  (proven)
// ---------------------------------------------------------------------------
__global__ void __launch_bounds__(256) embed_scatter(
    const int* __restrict__ lcid, const int* __restrict__ cmask,
    const float* __restrict__ emb, const float* __restrict__ lw,
    float* __restrict__ leafbuf, unsigned short* __restrict__ vecb,
    unsigned short* __restrict__ wb) {
  if (blockIdx.x >= 16384) {          // ---- cvt_w ----
    int i   = (blockIdx.x - 16384) * 256 + threadIdx.x;   // [0,16384)
    int row = i >> 5;
    uint4 r = {0u, 0u, 0u, 0u};
    if (row < NC) {
      const float4* v4 = (const float4*)lw;
      float4 x = v4[2 * i], y = v4[2 * i + 1];
      r.x = (unsigned)f2bf(x.x) | ((unsigned)f2bf(x.y) << 16);
      r.y = (unsigned)f2bf(x.z) | ((unsigned)f2bf(x.w) << 16);
      r.z = (unsigned)f2bf(y.x) | ((unsigned)f2bf(y.y) << 16);
      r.w = (unsigned)f2bf(y.z) | ((unsigned)f2bf(y.w) << 16);
    }
    ((uint4*)wb)[i] = r;
    return;
  }
  int rid  = blockIdx.x * 4 + (threadIdx.x >> 6);   // b*NL + l
  int lane = threadIdx.x & 63;
  int slot = lcid[2 * rid];
  int vid  = lcid[2 * rid + 1];
  int msk  = cmask[rid];
  int b    = rid >> 9;                               // / NL
  float4 v = {0.f, 0.f, 0.f, 0.f};
  if (msk) v = ((const float4*)(emb + (size_t)vid * ND))[lane];
  float ss = v.x * v.x + v.y * v.y + v.z * v.z + v.w * v.w;
#pragma unroll
  for (int off = 32; off > 0; off >>= 1) ss += __shfl_down(ss, off, 64);
  ss = __shfl(ss, 0, 64);
  float inv = 1.0f / (sqrtf(ss) + EPSF);   // msk==0: v=0 -> o=0 (no NaN)
  float4 o;
  o.x = v.x * inv; o.y = v.y * inv; o.z = v.z * inv; o.w = v.w * inv;
  ((float4*)(leafbuf + ((size_t)b * 512 + slot) * ND))[lane] = o;
  uint2 pk;
  pk.x = (unsigned)f2bf(o.x) | ((unsigned)f2bf(o.y) << 16);
  pk.y = (unsigned)f2bf(o.z) | ((unsigned)f2bf(o.w) << 16);
  ((uint2*)(vecb + ((size_t)b * NN + slot) * ND))[lane] = pk;
}

// ---------------------------------------------------------------------------
// Phase 2 (merged launch): blocks [0,128) = compose (round-6 PASSING kernel,
// body verbatim via reference-bound names); blocks [128,1152) = leaf-half
// GEMM (round-1 hardware-passed body). Shared memory is a UNION (114 KB) so
// every block allocates 114 KB -> ONE block per CU -> the round-1 poisoning
// mechanism (gemm co-resident on compose CUs, LDS-pipe contention) is
// physically excluded. No data deps between the two halves (leaf-gemm reads
// only embed outputs; compose writes outbuf/fsrcG for later launches).
// ---------------------------------------------------------------------------
struct ComposeSh {
  int4 sinfo4[NT];
  int ptr_[NT];
  int lsA[NT], rsA[NT];
  int lvl[NT], fsrc[NT];
  int schedS[NT], schedL[NT], schedR[NT];
  int offs[512], cnt[512], cnt2[512];
  unsigned char deadF[NT], liveF[NT], lzero[512];
  float a_st[16][256];
  float b_st[16][512];
  float s_st[16][512];
  int changed, smax;
};
struct LeafGemmSh { short As[256 * 64]; short Ws[128 * 64]; };
union FuseSh { ComposeSh c; LeafGemmSh g; };

__global__ void __launch_bounds__(1024) compose_leafgemm(
    const int* __restrict__ info, const int* __restrict__ lcid,
    const int* __restrict__ cmask, const float* __restrict__ leafbuf,
    float* __restrict__ outbuf, int* __restrict__ fsrcG,
    const short* __restrict__ vecbS, const short* __restrict__ wbs,
    const float* __restrict__ bias, float* __restrict__ out) {
  __shared__ FuseSh sh;
  const int tid  = threadIdx.x;
  const int lane = tid & 63;
  const int wav  = tid >> 6;

  if (blockIdx.x < NB) {
    // ================= compose (round-6 passing body, verbatim) =============
    const int b = blockIdx.x;
    int4 (&sinfo4)[NT] = sh.c.sinfo4;
    int (&ptr_)[NT] = sh.c.ptr_;
    int (&lsA)[NT] = sh.c.lsA;  int (&rsA)[NT] = sh.c.rsA;
    int (&lvl)[NT] = sh.c.lvl;  int (&fsrc)[NT] = sh.c.fsrc;
    int (&schedS)[NT] = sh.c.schedS; int (&schedL)[NT] = sh.c.schedL;
    int (&schedR)[NT] = sh.c.schedR;
    int (&offs)[512] = sh.c.offs; int (&cnt)[512] = sh.c.cnt;
    int (&cnt2)[512] = sh.c.cnt2;
    unsigned char (&deadF)[NT] = sh.c.deadF;
    unsigned char (&liveF)[NT] = sh.c.liveF;
    unsigned char (&lzero)[512] = sh.c.lzero;
    float (&a_st)[16][256] = sh.c.a_st;
    float (&b_st)[16][512] = sh.c.b_st;
    float (&s_st)[16][512] = sh.c.s_st;
    int &changed = sh.c.changed; int &smax = sh.c.smax;

    const float* lb = leafbuf + (size_t)b * 512 * ND;
    float*       ob = outbuf + (size_t)b * NT * ND;

    // ---- load step info + leaf-zero mask ----
    const int4* ib4 = (const int4*)(info + (size_t)b * NT * 4);
    for (int i = tid; i < NT; i += 1024) sinfo4[i] = ib4[i];
    if (tid < 512) lzero[tid] = 1;
    if (tid == 0) smax = 0;
    __syncthreads();
    if (tid < NL) {
      int row = lcid[((size_t)b * NL + tid) * 2];   // slots unique per batch
      lzero[row] = (cmask[(size_t)b * NL + tid] == 0) ? 1 : 0;
    }
    __syncthreads();

    // ---- last-writer scan (broadcast reads; one thread per step) ----
    const int t = tid;
    int4 m1 = {0, 0, 0, 0};
    if (t < NT) m1 = sinfo4[t];
    int l1 = -1, r1 = -1, f1 = -1;
    const int prow = 512 + t;
    for (int tp = 0; tp < NT; ++tp) {
      int4 wi = sinfo4[tp];
      if (wi.x > 0) {   // type-1/2 write row wi.y (in [512,1023))
        if (t < NT && tp < t) { if (wi.y == m1.z) l1 = tp; if (wi.y == m1.w) r1 = tp; }
        if (wi.y == prow) f1 = tp;
      }
    }
    __syncthreads();

    // ---- type-1 chain collapse via pointer jumping ----
    if (t < NT) {
      int v;
      if (m1.x == 2) v = SLOTC + t;
      else if (m1.x == 1) {
        if (m1.z < 512) v = m1.z;
        else v = (l1 >= 0) ? (STEPC + l1) : SRC_ZERO;
      } else v = SRC_ZERO;
      ptr_[t] = v;
    }
    __syncthreads();
    for (int it = 0; it < 10; ++it) {   // 2^10 covers any chain length <= 511
      int v = 0;
      if (t < NT) { v = ptr_[t]; if (v >= STEPC) v = ptr_[v - STEPC]; }
      __syncthreads();
      if (t < NT) ptr_[t] = v;
      __syncthreads();
    }

    // ---- resolve type-2 operands + final row sources ----
    auto normv = [&](int v) -> int {   // masked-out leaf row == zero vector
      if (v >= 0 && v < 512 && lzero[v]) return SRC_ZERO;
      return v;
    };
    auto collapseW = [&](int wstep) -> int {
      int v = (sinfo4[wstep].x == 2) ? (SLOTC + wstep) : ptr_[wstep];
      return normv(v);
    };
    if (t < NT) {
      if (m1.x == 2) {
        int a = (m1.z < 512) ? normv(m1.z) : ((l1 >= 0) ? collapseW(l1) : SRC_ZERO);
        int c = (m1.w < 512) ? normv(m1.w) : ((r1 >= 0) ? collapseW(r1) : SRC_ZERO);
        lsA[t] = a; rsA[t] = c;
        deadF[t] = (a == SRC_ZERO || c == SRC_ZERO) ? 1 : 0;
      } else {
        deadF[t] = 0;
      }
      liveF[t] = 0;
      fsrc[t] = (f1 >= 0) ? collapseW(f1) : SRC_ZERO;
    }
    __syncthreads();

    // ---- zero propagation fixpoint ----
    for (int rounds = 0; rounds < NT; ++rounds) {
      if (tid == 0) changed = 0;
      __syncthreads();
      if (t < NT && m1.x == 2 && !deadF[t]) {
        int a = lsA[t], c = rsA[t];
        if (a >= SLOTC && deadF[a - SLOTC]) { a = SRC_ZERO; lsA[t] = a; }
        if (c >= SLOTC && deadF[c - SLOTC]) { c = SRC_ZERO; rsA[t] = c; }
        if (a == SRC_ZERO || c == SRC_ZERO) { deadF[t] = 1; changed = 1; }
      }
      __syncthreads();
      if (!changed) break;
      __syncthreads();
    }

    // ---- backward liveness ----
    if (t < NT) {
      int f = fsrc[t];
      if (f >= SLOTC && deadF[f - SLOTC]) { f = SRC_ZERO; fsrc[t] = f; }
      if (f >= SLOTC) liveF[f - SLOTC] = 1;
    }
    __syncthreads();
    for (int rounds = 0; rounds < NT; ++rounds) {
      if (tid == 0) changed = 0;
      __syncthreads();
      if (t < NT && m1.x == 2 && liveF[t] && !deadF[t]) {
        int a = lsA[t], c = rsA[t];
        if (a >= SLOTC && !liveF[a - SLOTC]) { liveF[a - SLOTC] = 1; changed = 1; }
        if (c >= SLOTC && !liveF[c - SLOTC]) { liveF[c - SLOTC] = 1; changed = 1; }
      }
      __syncthreads();
      if (!changed) break;
      __syncthreads();
    }

    const bool isLive = (t < NT && m1.x == 2 && liveF[t] && !deadF[t]);

    // ---- ASAP levels via monotone fixpoint ----
    if (t < NT) lvl[t] = 0;
    __syncthreads();
    for (int rounds = 0; rounds < NT; ++rounds) {
      if (tid == 0) changed = 0;
      __syncthreads();
      if (isLive) {
        int nl = 1, a = lsA[t], c = rsA[t];
        if (a >= SLOTC) { int dl = lvl[a - SLOTC] + 1; if (dl > nl) nl = dl; }
        if (c >= SLOTC) { int dl = lvl[c - SLOTC] + 1; if (dl > nl) nl = dl; }
        if (nl > lvl[t]) { lvl[t] = nl; changed = 1; }
      }
      __syncthreads();
      if (!changed) break;
      __syncthreads();
    }
    if (isLive) atomicMax(&smax, lvl[t]);

    // ---- bucket ops by level ----
    if (tid < 512) { cnt[tid] = 0; cnt2[tid] = 0; }
    __syncthreads();
    if (isLive) atomicAdd(&cnt[lvl[t]], 1);
    __syncthreads();
    if (tid < 512) offs[tid] = cnt[tid];
    __syncthreads();
    for (int k = 1; k < 512; k <<= 1) {   // inclusive prefix over levels
      int v = 0;
      if (tid < 512) { v = offs[tid]; if (tid >= k) v += offs[tid - k]; }
      __syncthreads();
      if (tid < 512) offs[tid] = v;
      __syncthreads();
    }
    if (isLive) {
      int d = lvl[t];
      int pos = offs[d - 1] + atomicAdd(&cnt2[d], 1);   // d>=1 always
      schedS[pos] = t; schedL[pos] = lsA[t]; schedR[pos] = rsA[t];
    }
    __syncthreads();

    // ---- level-parallel execution: one op per wave, packed inner loop ----
    const int maxd = smax;
    for (int d = 1; d <= maxd; ++d) {
      const int base = offs[d - 1];
      const int nops = cnt[d];
      const int nch  = (nops + 15) >> 4;
      for (int ch = 0; ch < nch; ++ch) {
        int rel = ch * 16 + wav;
        if (rel < nops) {           // wave-uniform predicate
          int my = base + rel;
          int tt = schedS[my], ls = schedL[my], rs = schedR[my];
          const float* pa = (ls < 512) ? lb + (size_t)ls * ND
                                       : ob + (size_t)(ls - SLOTC) * ND;
          const float* pb = (rs < 512) ? lb + (size_t)rs * ND
                                       : ob + (size_t)(rs - SLOTC) * ND;
          float4 av = ((const float4*)pa)[lane];
          float4 bv = ((const float4*)pb)[lane];
          float nx = __shfl(bv.x, (lane + 1) & 63, 64);
          float4 sv = {bv.y, bv.z, bv.w, nx};
          ((float4*)a_st[wav])[lane]      = av;
          ((float4*)b_st[wav])[lane]      = bv;
          ((float4*)b_st[wav])[lane + 64] = bv;   // doubled for mod-256 window
          ((float4*)s_st[wav])[lane]      = sv;
          ((float4*)s_st[wav])[lane + 64] = sv;
          const float4* a4 = (const float4*)a_st[wav];
          const float4* b4 = (const float4*)b_st[wav];
          const float4* s4 = (const float4*)s_st[wav];
          f32x2 q0 = {0.f, 0.f}, q1 = {0.f, 0.f}, q2 = {0.f, 0.f}, q3 = {0.f, 0.f};
          float4 B0 = b4[lane];
          float4 S0 = s4[lane];
#pragma unroll 8
          for (int i = 0; i < 64; ++i) {
            float4 A  = a4[i];             // uniform -> LDS broadcast
            float4 B1 = b4[lane + i + 1];  // rolling windows, conflict-free
            float4 S1 = s4[lane + i + 1];
            f32x2 Axy = {A.x, A.y},  Azw = {A.z, A.w};
            f32x2 Bxy = {B0.x, B0.y}, Bzw = {B0.z, B0.w};
            f32x2 Sxy = {S0.x, S0.y}, Szw = {S0.z, S0.w};
            f32x2 B1xy = {B1.x, B1.y}, S1xy = {S1.x, S1.y};
            q0 += Axy * Bxy;  q0 += Azw * Bzw;
            q1 += Axy * Sxy;  q1 += Azw * Szw;
            q2 += Axy * Bzw;  q2 += Azw * B1xy;
            q3 += Axy * Szw;  q3 += Azw * S1xy;
            B0 = B1; S0 = S1;
          }
          float c0 = q0.x + q0.y, c1 = q1.x + q1.y;
          float c2 = q2.x + q2.y, c3 = q3.x + q3.y;
          float ss = c0 * c0 + c1 * c1 + c2 * c2 + c3 * c3;
#pragma unroll
          for (int off = 32; off > 0; off >>= 1) ss += __shfl_down(ss, off, 64);
          ss = __shfl(ss, 0, 64);
          float inv = 1.f / (sqrtf(ss) + EPSF);
          float4 res;
          res.x = c0 * inv; res.y = c1 * inv; res.z = c2 * inv; res.w = c3 * inv;
          ((float4*)(ob + (size_t)tt * ND))[lane] = res;
        }
        // no intra-level barrier: staging wave-private, deps cross-level
      }
      __syncthreads();   // level boundary
    }

    // ---- export final-row sources for the gather kernel ----
    for (int i = tid; i < NT; i += 1024) fsrcG[b * NT + i] = fsrc[i];
    return;
  }

  // ============== leaf-half GEMM (round-1 hardware-passed body) ============
  // 256x128 tile, 16 waves (8x2), rows n<512 only. Hidden under compose.
  const int gidx = blockIdx.x - NB;
  const int b  = gidx >> 3;
  const int mt = (gidx >> 2) & 1;     // 2 m-tiles of 256 leaf rows
  const int ct = gidx & 3;            // 4 col-tiles of 128
  const short* A = vecbS + ((size_t)b * NN + mt * 256) * ND;
  const int c0   = ct * 128;
  const int wr   = wav >> 1;          // 0..7 : 32-row strip
  const int wc   = wav & 1;           // 0..1 : 64-col strip
  const int frow = lane & 15;
  const int quad = lane >> 4;
  f32x4 acc[2][4];
#pragma unroll
  for (int i = 0; i < 2; ++i)
#pragma unroll
    for (int j = 0; j < 4; ++j) acc[i][j] = (f32x4){0.f, 0.f, 0.f, 0.f};

  for (int k0 = 0; k0 < ND; k0 += 64) {
#pragma unroll
    for (int i = 0; i < 2; ++i) {
      int idx = i * 1024 + tid;
      int row = idx >> 3;
      int chn = idx & 7;
      const short* ga = A + (size_t)row * ND + k0 + chn * 8;
      __builtin_amdgcn_global_load_lds(
          (const __attribute__((address_space(1))) void*)ga,
          (__attribute__((address_space(3))) void*)(sh.g.As + idx * 8), 16, 0, 0);
    }
    {
      int row = tid >> 3;
      int chn = tid & 7;
      const short* gw = wbs + (size_t)(c0 + row) * ND + k0 + chn * 8;
      __builtin_amdgcn_global_load_lds(
          (const __attribute__((address_space(1))) void*)gw,
          (__attribute__((address_space(3))) void*)(sh.g.Ws + tid * 8), 16, 0, 0);
    }
    __syncthreads();
#pragma unroll
    for (int ks = 0; ks < 2; ++ks) {
      short8 af[2], wf[4];
#pragma unroll
      for (int mi = 0; mi < 2; ++mi)
        af[mi] = *(const short8*)(sh.g.As + (wr * 32 + mi * 16 + frow) * 64 + ks * 32 + quad * 8);
#pragma unroll
      for (int ci = 0; ci < 4; ++ci)
        wf[ci] = *(const short8*)(sh.g.Ws + (wc * 64 + ci * 16 + frow) * 64 + ks * 32 + quad * 8);
#pragma unroll
      for (int mi = 0; mi < 2; ++mi)
#pragma unroll
        for (int ci = 0; ci < 4; ++ci)
          acc[mi][ci] = __builtin_amdgcn_mfma_f32_16x16x32_bf16(
              af[mi], wf[ci], acc[mi][ci], 0, 0, 0);
    }
    __syncthreads();
  }
#pragma unroll
  for (int mi = 0; mi < 2; ++mi) {
#pragma unroll
    for (int ci = 0; ci < 4; ++ci) {
      int col = c0 + wc * 64 + ci * 16 + frow;
      if (col < NC) {
        float bv = bias[col];
#pragma unroll
        for (int r = 0; r < 4; ++r) {
          int n = mt * 256 + wr * 32 + mi * 16 + quad * 4 + r;   // < 512
          out[((size_t)b * NN + n) * NC + col] = acc[mi][ci][r] + bv;
        }
      }
    }
  }
}

// ---------------------------------------------------------------------------
// Phase 3: full-grid gather of parent rows -> vecb (bf16). One wave per row.
// (proven; fsrcG now lives in out's batch-0 internal-row region)
// ---------------------------------------------------------------------------
__global__ void __launch_bounds__(256) gather_rows(
    const int* __restrict__ fsrcG, const float* __restrict__ leafbuf,
    const float* __restrict__ outbuf, unsigned short* __restrict__ vecb) {
  int rid  = blockIdx.x * 4 + (threadIdx.x >> 6);   // b*NT + idx  (exact grid)
  int lane = threadIdx.x & 63;
  int b    = rid / NT;
  int idx  = rid - b * NT;
  int s    = fsrcG[rid];
  float4 v = {0.f, 0.f, 0.f, 0.f};
  if (s >= 0) {
    const float* src = (s < 512)
        ? (leafbuf + ((size_t)b * 512 + s) * ND)
        : (outbuf + ((size_t)b * NT + (s - SLOTC)) * ND);
    v = ((const float4*)src)[lane];
  }
  uint2 pk;
  pk.x = (unsigned)f2bf(v.x) | ((unsigned)f2bf(v.y) << 16);
  pk.y = (unsigned)f2bf(v.z) | ((unsigned)f2bf(v.w) << 16);
  ((uint2*)(vecb + ((size_t)b * NN + 512 + idx) * ND))[lane] = pk;
}

// ---------------------------------------------------------------------------
// Phase 4: internal-row GEMM (n in [512,1023)) — round-6's proven swizzled
// gemm with per-batch internal row mapping. Flat grid 2048, XCD-grouped:
// i -> q=i>>5, t=i&31, mtile=q*8+(t&7) in [0,512), c=t>>3; b=mtile>>2,
// mt=mtile&3. Col-siblings share i%8 -> same XCD -> A-tile from L2.
// mt=3 tile has 127 rows: store guard n<NN; A-row overrun reads land in the
// next batch / wb region of ws (in-bounds, store-guarded, harmless).
// Overwrites the fsrcG staging bytes in d_out (gather already consumed them).
// ---------------------------------------------------------------------------
union GemmSh {
  struct { short As[128 * 64]; short Ws[128 * 64]; } s;   // 32 KB
  float epi[4][16][65];                                   // 16.6 KB (padded)
};

__global__ void __launch_bounds__(256) gemm_int(
    const short* __restrict__ A, const short* __restrict__ W,
    const float* __restrict__ bias, float* __restrict__ out) {
  __shared__ GemmSh sh;
  int i = blockIdx.x;                       // [0,2048)
  int mtile = (i >> 5) * 8 + (i & 7);       // [0,512)
  int c     = (i >> 3) & 3;                 // [0,4)
  int b     = mtile >> 2;
  int mt    = mtile & 3;
  size_t arow = (size_t)b * NN + 512 + mt * 128;   // global A-row base
  int tid  = threadIdx.x;
  int lane = tid & 63;
  int w    = tid >> 6;
  int c0   = c * 128;
  int wm   = (w & 1) * 64;
  int wc   = (w >> 1) * 64;
  int frow = lane & 15;
  int quad = lane >> 4;
  f32x4 acc[4][4];
#pragma unroll
  for (int a = 0; a < 4; ++a)
#pragma unroll
    for (int j = 0; j < 4; ++j) acc[a][j] = (f32x4){0.f, 0.f, 0.f, 0.f};

  for (int k0 = 0; k0 < ND; k0 += 64) {
#pragma unroll
    for (int a = 0; a < 4; ++a) {
      int idx = a * 256 + tid;
      int row = idx >> 3;
      int ch  = idx & 7;
      int chs = ch ^ (row & 7);   // pre-swizzled source chunk (rule #21)
      const short* ga = A + (arow + row) * ND + k0 + chs * 8;
      const short* gw = W + (size_t)(c0 + row) * ND + k0 + chs * 8;
      __builtin_amdgcn_global_load_lds(
          (const __attribute__((address_space(1))) void*)ga,
          (__attribute__((address_space(3))) void*)(sh.s.As + idx * 8), 16, 0, 0);
      __builtin_amdgcn_global_load_lds(
          (const __attribute__((address_space(1))) void*)gw,
          (__attribute__((address_space(3))) void*)(sh.s.Ws + idx * 8), 16, 0, 0);
    }
    __syncthreads();
#pragma unroll
    for (int ks = 0; ks < 2; ++ks) {
      short8 af[4], wf[4];
#pragma unroll
      for (int mi = 0; mi < 4; ++mi) {
        int r = wm + mi * 16 + frow;
        int cc = (ks * 4 + quad) ^ (r & 7);
        af[mi] = *(const short8*)(sh.s.As + r * 64 + cc * 8);
      }
#pragma unroll
      for (int ci = 0; ci < 4; ++ci) {
        int r = wc + ci * 16 + frow;
        int cc = (ks * 4 + quad) ^ (r & 7);
        wf[ci] = *(const short8*)(sh.s.Ws + r * 64 + cc * 8);
      }
#pragma unroll
      for (int mi = 0; mi < 4; ++mi)
#pragma unroll
        for (int ci = 0; ci < 4; ++ci)
          acc[mi][ci] = __builtin_amdgcn_mfma_f32_16x16x32_bf16(
              af[mi], wf[ci], acc[mi][ci], 0, 0, 0);
    }
    __syncthreads();
  }

  // ---- coalesced epilogue: per-wave 16x64 transpose through LDS ----
  int colg = c0 + wc + lane;                       // this lane's output column
  float bv = (colg < NC) ? bias[colg] : 0.f;
#pragma unroll
  for (int mi = 0; mi < 4; ++mi) {
#pragma unroll
    for (int ci = 0; ci < 4; ++ci)
#pragma unroll
      for (int r = 0; r < 4; ++r)
        sh.epi[w][quad * 4 + r][ci * 16 + frow] = acc[mi][ci][r];
    // same-wave DS in-order: the reads below see the writes above
    if (colg < NC) {
      int nbase = 512 + mt * 128 + wm + mi * 16;
#pragma unroll
      for (int rr = 0; rr < 16; ++rr) {
        int n = nbase + rr;
        if (n < NN)
          out[((size_t)b * NN + n) * NC + colg] = sh.epi[w][rr][lane] + bv;
      }
    }
  }
}

// ---------------------------------------------------------------------------
// Workspace layout (201,392,128 bytes — unchanged):
//   [0)           leafbuf fp32 [B][512][D]  =  67,108,864 B
//   [67108864)    outbuf  fp32 [B][511][D]  =  66,977,792 B
//   [134086656)   vecb    bf16 [B][1023][D] =  67,043,328 B
//   [201129984)   wb      bf16 [512][D]     =     262,144 B
// fsrcG (128*511 ints = 261,632 B) staged in d_out's BATCH-0 INTERNAL region
// (float offset 512*NC): leaf-gemm (same launch as compose) writes only
// rows n<512 -> no overlap; gather reads it; gemm_int overwrites it after.
// ---------------------------------------------------------------------------
extern "C" void kernel_launch(void* const* d_in, const int* in_sizes, int n_in,
                              void* d_out, int out_size, void* d_ws, size_t ws_size,
                              hipStream_t stream) {
  const int*   lcid  = (const int*)d_in[1];
  const int*   cmask = (const int*)d_in[2];
  const int*   cinfo = (const int*)d_in[3];
  const float* emb   = (const float*)d_in[4];
  const float* lw    = (const float*)d_in[5];
  const float* lbias = (const float*)d_in[6];
  float*       out   = (float*)d_out;

  char* ws = (char*)d_ws;
  float*          leafbuf = (float*)ws;
  float*          outbuf  = (float*)(ws + 67108864);
  unsigned short* vecb    = (unsigned short*)(ws + 134086656);
  unsigned short* wb      = (unsigned short*)(ws + 201129984);
  int*            fsrcG   = (int*)d_out + (size_t)512 * NC;   // batch-0 internal rows

  embed_scatter<<<16448, 256, 0, stream>>>(lcid, cmask, emb, lw,
                                           leafbuf, vecb, wb);
  compose_leafgemm<<<NB + 1024, 1024, 0, stream>>>(
      cinfo, lcid, cmask, leafbuf, outbuf, fsrcG,
      (const short*)vecb, (const short*)wb, lbias, out);
  gather_rows<<<NB * NT / 4, 256, 0, stream>>>(fsrcG, leafbuf, outbuf, vecb);
  gemm_int<<<2048, 256, 0, stream>>>(
      (const short*)vecb, (const short*)wb, lbias, out);
}